// Round 1
// baseline (829.061 us; speedup 1.0000x reference)
//
#include <hip/hip_runtime.h>

// GAT 3-layer on MI355X.
// Pipeline per call:
//   CSR build (hist -> scan -> scatter)  [int atomics only]
//   h0 = x @ lin_w + lin_b               [fp32 tiled GEMM, N=64 fixed]
//   per layer: h' = h @ w ; hs/hd = h'.a_s/a_d ; gather-aggregate per node
//   final layer fuses bias + L2 row normalize.
// Wave(64) = feature dim(64): lane == feature everywhere.

constexpr float NEG_SLOPE = 0.2f;

// ---------------- GEMM: C[M x 64] = A[M x K] @ B[K x 64] (+ optional bias) ---
__global__ __launch_bounds__(256) void gemm64(
    const float* __restrict__ A, const float* __restrict__ B,
    const float* __restrict__ bias, float* __restrict__ C, int M, int K)
{
    __shared__ float As[16][64];   // As[k][r] (transposed for float4 row reads)
    __shared__ float Bs[16][64];   // Bs[k][c]
    const int tid  = threadIdx.x;
    const int row0 = blockIdx.x * 64;
    const int tr = tid >> 4;              // 0..15 -> rows 4*tr..4*tr+3
    const int tc = tid & 15;              // 0..15 -> cols 4*tc..4*tc+3
    const int ar = tid >> 2;              // 0..63 (row in A tile)
    const int ak = (tid & 3) << 2;        // k chunk (float4)
    const int bk = tid >> 4;              // 0..15 (row in B tile)
    const int bc = (tid & 15) << 2;       // col chunk (float4)

    float acc[4][4] = {};

    for (int k0 = 0; k0 < K; k0 += 16) {
        float4 av = make_float4(0.f, 0.f, 0.f, 0.f);
        const int arow = row0 + ar;
        if (arow < M) av = *(const float4*)(A + (size_t)arow * K + k0 + ak);
        const float4 bv = *(const float4*)(B + (size_t)(k0 + bk) * 64 + bc);
        __syncthreads();
        As[ak + 0][ar] = av.x;
        As[ak + 1][ar] = av.y;
        As[ak + 2][ar] = av.z;
        As[ak + 3][ar] = av.w;
        *(float4*)(&Bs[bk][bc]) = bv;
        __syncthreads();
        #pragma unroll
        for (int kk = 0; kk < 16; ++kk) {
            const float4 a4 = *(const float4*)(&As[kk][tr << 2]);
            const float4 b4 = *(const float4*)(&Bs[kk][tc << 2]);
            const float aa[4] = {a4.x, a4.y, a4.z, a4.w};
            const float bb[4] = {b4.x, b4.y, b4.z, b4.w};
            #pragma unroll
            for (int i = 0; i < 4; ++i)
                #pragma unroll
                for (int j = 0; j < 4; ++j)
                    acc[i][j] = fmaf(aa[i], bb[j], acc[i][j]);
        }
    }

    const int c = tc << 2;
    float b0 = 0.f, b1 = 0.f, b2 = 0.f, b3 = 0.f;
    if (bias) { b0 = bias[c]; b1 = bias[c + 1]; b2 = bias[c + 2]; b3 = bias[c + 3]; }
    #pragma unroll
    for (int i = 0; i < 4; ++i) {
        const int r = row0 + (tr << 2) + i;
        if (r < M) {
            float4 v;
            v.x = acc[i][0] + b0;
            v.y = acc[i][1] + b1;
            v.z = acc[i][2] + b2;
            v.w = acc[i][3] + b3;
            *(float4*)(C + (size_t)r * 64 + c) = v;
        }
    }
}

// ---------------- per-node attention dots: hs[i]=h[i].a_s, hd[i]=h[i].a_d ----
__global__ __launch_bounds__(256) void node_dots(
    const float* __restrict__ h, const float* __restrict__ a_s,
    const float* __restrict__ a_d, float* __restrict__ hs,
    float* __restrict__ hd, int n)
{
    const int wid  = (blockIdx.x * blockDim.x + threadIdx.x) >> 6;
    const int lane = threadIdx.x & 63;
    if (wid >= n) return;
    const float v = h[(size_t)wid * 64 + lane];
    float s = v * a_s[lane];
    float d = v * a_d[lane];
    #pragma unroll
    for (int off = 32; off; off >>= 1) {
        s += __shfl_down(s, off);
        d += __shfl_down(d, off);
    }
    if (lane == 0) { hs[wid] = s; hd[wid] = d; }
}

// ---------------- CSR build --------------------------------------------------
__global__ __launch_bounds__(256) void edge_hist(
    const int* __restrict__ dst, int* __restrict__ cnt, int e)
{
    const int i = blockIdx.x * blockDim.x + threadIdx.x;
    if (i < e) atomicAdd(&cnt[dst[i]], 1);
}

// block: 256 threads, 1024 elements; exclusive scan chunk, emit block total
__global__ __launch_bounds__(256) void scan1(
    const int* __restrict__ cnt, int* __restrict__ out,
    int* __restrict__ bsum, int n)
{
    __shared__ int wsum[4];
    const int tid  = threadIdx.x;
    const int lane = tid & 63;
    const int w    = tid >> 6;
    const int base = blockIdx.x * 1024;
    int vals[4];
    int tsum = 0;
    #pragma unroll
    for (int i = 0; i < 4; ++i) {
        const int idx = base + tid * 4 + i;
        vals[i] = (idx < n) ? cnt[idx] : 0;
        tsum += vals[i];
    }
    int x = tsum;  // inclusive wave scan of per-thread sums
    #pragma unroll
    for (int off = 1; off < 64; off <<= 1) {
        const int y = __shfl_up(x, off);
        if (lane >= off) x += y;
    }
    if (lane == 63) wsum[w] = x;
    __syncthreads();
    int wofs = 0;
    for (int k = 0; k < w; ++k) wofs += wsum[k];
    int excl = wofs + x - tsum;
    #pragma unroll
    for (int i = 0; i < 4; ++i) {
        const int idx = base + tid * 4 + i;
        if (idx < n) out[idx] = excl;
        excl += vals[i];
    }
    if (tid == 255) bsum[blockIdx.x] = wofs + x;
}

// single block of 128 threads: exclusive scan of block sums in place
__global__ __launch_bounds__(128) void scan2(int* __restrict__ b, int nb)
{
    __shared__ int wtot[2];
    const int tid = threadIdx.x;
    const int lane = tid & 63;
    const int w = tid >> 6;
    const int v = (tid < nb) ? b[tid] : 0;
    int x = v;
    #pragma unroll
    for (int off = 1; off < 64; off <<= 1) {
        const int y = __shfl_up(x, off);
        if (lane >= off) x += y;
    }
    if (lane == 63) wtot[w] = x;
    __syncthreads();
    const int add = (w == 1) ? wtot[0] : 0;
    if (tid < nb) b[tid] = add + x - v;
}

__global__ __launch_bounds__(256) void scan3(
    int* __restrict__ out, const int* __restrict__ bsum, int n, int total)
{
    const int idx = blockIdx.x * blockDim.x + threadIdx.x;
    if (idx < n) out[idx] += bsum[idx >> 10];
    if (idx == 0) out[n] = total;
}

__global__ __launch_bounds__(256) void edge_scatter(
    const int* __restrict__ src, const int* __restrict__ dst,
    int* __restrict__ pos, int* __restrict__ ssrc, int e)
{
    const int i = blockIdx.x * blockDim.x + threadIdx.x;
    if (i < e) {
        const int p = atomicAdd(&pos[dst[i]], 1);
        ssrc[p] = src[i];
    }
}

// ---------------- gather aggregation: one wave per node, lane = feature ------
// MODE 0: +bias, ReLU.   MODE 1: +bias, L2 row-normalize (final layer).
template <int MODE>
__global__ __launch_bounds__(256) void gat_agg(
    const float* __restrict__ hp, const float* __restrict__ hs,
    const float* __restrict__ hd, const int* __restrict__ offs,
    const int* __restrict__ ssrc, const float* __restrict__ bias,
    float* __restrict__ out, int n)
{
    const int wid  = (blockIdx.x * blockDim.x + threadIdx.x) >> 6;
    const int lane = threadIdx.x & 63;
    if (wid >= n) return;

    const float hdi = hd[wid];

    // self-loop (reference appends loop edges for every node)
    float e = hs[wid] + hdi;
    e = (e > 0.f) ? e : NEG_SLOPE * e;
    float ex  = __expf(e);
    float den = ex;
    float acc = ex * hp[(size_t)wid * 64 + lane];

    const int start = offs[wid];
    const int end   = offs[wid + 1];
    for (int j = start; j < end; ++j) {
        const int s = ssrc[j];
        float e2 = hs[s] + hdi;
        e2 = (e2 > 0.f) ? e2 : NEG_SLOPE * e2;
        const float ex2 = __expf(e2);
        den += ex2;
        acc = fmaf(ex2, hp[(size_t)s * 64 + lane], acc);
    }

    float v = acc / (den + 1e-16f) + bias[lane];
    if (MODE == 0) {
        v = fmaxf(v, 0.f);
    } else {
        float sq = v * v;
        #pragma unroll
        for (int off = 32; off; off >>= 1) sq += __shfl_xor(sq, off);
        v = v / fmaxf(sqrtf(sq), 1e-12f);
    }
    out[(size_t)wid * 64 + lane] = v;
}

// ---------------- launch -----------------------------------------------------
extern "C" void kernel_launch(void* const* d_in, const int* in_sizes, int n_in,
                              void* d_out, int out_size, void* d_ws, size_t ws_size,
                              hipStream_t stream)
{
    const float* x     = (const float*)d_in[0];
    const int*   src   = (const int*)d_in[1];
    const int*   dst   = (const int*)d_in[2];
    const float* lin_w = (const float*)d_in[3];
    const float* lin_b = (const float*)d_in[4];
    const float* w1  = (const float*)d_in[5];
    const float* a1s = (const float*)d_in[6];
    const float* a1d = (const float*)d_in[7];
    const float* b1  = (const float*)d_in[8];
    const float* w2  = (const float*)d_in[9];
    const float* a2s = (const float*)d_in[10];
    const float* a2d = (const float*)d_in[11];
    const float* b2  = (const float*)d_in[12];
    const float* w3  = (const float*)d_in[13];
    const float* a3s = (const float*)d_in[14];
    const float* a3d = (const float*)d_in[15];
    const float* b3  = (const float*)d_in[16];

    const int n = in_sizes[0] / 256;   // 100000 nodes
    const int E = in_sizes[1];         // 1280000 edges

    // workspace carve-up (256B aligned)
    char* wsp = (char*)d_ws;
    auto alloc = [&](size_t bytes) -> void* {
        void* p = (void*)wsp;
        wsp += (bytes + 255) & ~(size_t)255;
        return p;
    };
    float* bufA = (float*)alloc((size_t)n * 64 * sizeof(float));
    float* bufB = (float*)alloc((size_t)n * 64 * sizeof(float));
    float* hs   = (float*)alloc((size_t)n * sizeof(float));
    float* hd   = (float*)alloc((size_t)n * sizeof(float));
    int*   offs = (int*)alloc((size_t)(n + 1) * sizeof(int));
    int*   pos  = (int*)alloc((size_t)n * sizeof(int));   // doubles as cnt
    int*   bsum = (int*)alloc(1024 * sizeof(int));
    int*   ssrc = (int*)alloc((size_t)E * sizeof(int));

    const int edgeBlocks = (E + 255) / 256;
    const int nodeWaveBlocks = (n + 3) / 4;          // 4 waves / 256-thread block
    const int gemmBlocks = (n + 63) / 64;
    const int nScanBlocks = (n + 1023) / 1024;

    // ---- CSR build (reused by all 3 layers) ----
    hipMemsetAsync(pos, 0, (size_t)n * sizeof(int), stream);
    edge_hist<<<edgeBlocks, 256, 0, stream>>>(dst, pos, E);
    scan1<<<nScanBlocks, 256, 0, stream>>>(pos, offs, bsum, n);
    scan2<<<1, 128, 0, stream>>>(bsum, nScanBlocks);
    scan3<<<(n + 255) / 256, 256, 0, stream>>>(offs, bsum, n, E);
    hipMemcpyAsync(pos, offs, (size_t)n * sizeof(int), hipMemcpyDeviceToDevice, stream);
    edge_scatter<<<edgeBlocks, 256, 0, stream>>>(src, dst, pos, ssrc, E);

    // ---- feature_pre linear: h0 = x @ lin_w + lin_b -> bufA ----
    gemm64<<<gemmBlocks, 256, 0, stream>>>(x, lin_w, lin_b, bufA, n, 256);

    // ---- layer 1 ----
    gemm64<<<gemmBlocks, 256, 0, stream>>>(bufA, w1, nullptr, bufB, n, 64);
    node_dots<<<nodeWaveBlocks, 256, 0, stream>>>(bufB, a1s, a1d, hs, hd, n);
    gat_agg<0><<<nodeWaveBlocks, 256, 0, stream>>>(bufB, hs, hd, offs, ssrc, b1, bufA, n);

    // ---- layer 2 ----
    gemm64<<<gemmBlocks, 256, 0, stream>>>(bufA, w2, nullptr, bufB, n, 64);
    node_dots<<<nodeWaveBlocks, 256, 0, stream>>>(bufB, a2s, a2d, hs, hd, n);
    gat_agg<0><<<nodeWaveBlocks, 256, 0, stream>>>(bufB, hs, hd, offs, ssrc, b2, bufA, n);

    // ---- layer 3 + normalize -> d_out ----
    gemm64<<<gemmBlocks, 256, 0, stream>>>(bufA, w3, nullptr, bufB, n, 64);
    node_dots<<<nodeWaveBlocks, 256, 0, stream>>>(bufB, a3s, a3d, hs, hd, n);
    gat_agg<1><<<nodeWaveBlocks, 256, 0, stream>>>(bufB, hs, hd, offs, ssrc, b3,
                                                   (float*)d_out, n);
}

// Round 2
// 578.103 us; speedup vs baseline: 1.4341x; 1.4341x over previous
//
#include <hip/hip_runtime.h>

// GAT 3-layer on MI355X.
//   CSR build (hist -> scan -> scatter)  [int atomics only]
//   h0 = x @ lin_w + lin_b               [fp32 tiled GEMM, N=64 fixed]
//   per layer: h' = h @ w (dots fused in epilogue); gather-aggregate per node
//   final layer fuses bias + L2 row normalize.
// gat_agg: one wave per node, 4 edge slots x 16 lanes (float4/lane) ->
// 4-8 independent gathers in flight per wave (latency-bound fix, round 1).

constexpr float NEG_SLOPE = 0.2f;

// ---------------- GEMM: C[M x 64] = A[M x K] @ B[K x 64] (+ optional bias) ---
// DOTS: also emit hs[r] = C_row . a_s, hd[r] = C_row . a_d (pre-bias h').
template <bool DOTS>
__global__ __launch_bounds__(256) void gemm64(
    const float* __restrict__ A, const float* __restrict__ B,
    const float* __restrict__ bias, float* __restrict__ C, int M, int K,
    const float* __restrict__ a_s, const float* __restrict__ a_d,
    float* __restrict__ hs, float* __restrict__ hd)
{
    __shared__ float As[16][64];   // As[k][r] (transposed for float4 row reads)
    __shared__ float Bs[16][64];   // Bs[k][c]
    const int tid  = threadIdx.x;
    const int row0 = blockIdx.x * 64;
    const int tr = tid >> 4;              // 0..15 -> rows 4*tr..4*tr+3
    const int tc = tid & 15;              // 0..15 -> cols 4*tc..4*tc+3
    const int ar = tid >> 2;              // 0..63 (row in A tile)
    const int ak = (tid & 3) << 2;        // k chunk (float4)
    const int bk = tid >> 4;              // 0..15 (row in B tile)
    const int bc = (tid & 15) << 2;       // col chunk (float4)

    float acc[4][4] = {};

    for (int k0 = 0; k0 < K; k0 += 16) {
        float4 av = make_float4(0.f, 0.f, 0.f, 0.f);
        const int arow = row0 + ar;
        if (arow < M) av = *(const float4*)(A + (size_t)arow * K + k0 + ak);
        const float4 bv = *(const float4*)(B + (size_t)(k0 + bk) * 64 + bc);
        __syncthreads();
        As[ak + 0][ar] = av.x;
        As[ak + 1][ar] = av.y;
        As[ak + 2][ar] = av.z;
        As[ak + 3][ar] = av.w;
        *(float4*)(&Bs[bk][bc]) = bv;
        __syncthreads();
        #pragma unroll
        for (int kk = 0; kk < 16; ++kk) {
            const float4 a4 = *(const float4*)(&As[kk][tr << 2]);
            const float4 b4 = *(const float4*)(&Bs[kk][tc << 2]);
            const float aa[4] = {a4.x, a4.y, a4.z, a4.w};
            const float bb[4] = {b4.x, b4.y, b4.z, b4.w};
            #pragma unroll
            for (int i = 0; i < 4; ++i)
                #pragma unroll
                for (int j = 0; j < 4; ++j)
                    acc[i][j] = fmaf(aa[i], bb[j], acc[i][j]);
        }
    }

    const int c = tc << 2;
    float b0 = 0.f, b1 = 0.f, b2 = 0.f, b3 = 0.f;
    if (bias) { b0 = bias[c]; b1 = bias[c + 1]; b2 = bias[c + 2]; b3 = bias[c + 3]; }
    #pragma unroll
    for (int i = 0; i < 4; ++i) {
        const int r = row0 + (tr << 2) + i;
        if (r < M) {
            float4 v;
            v.x = acc[i][0] + b0;
            v.y = acc[i][1] + b1;
            v.z = acc[i][2] + b2;
            v.w = acc[i][3] + b3;
            *(float4*)(C + (size_t)r * 64 + c) = v;
        }
    }

    if (DOTS) {
        // row dot with a_s/a_d: partial over this thread's 4 cols, then
        // shuffle-reduce across the 16 lanes sharing the row (offsets < 16).
        const float4 asv = *(const float4*)(a_s + c);
        const float4 adv = *(const float4*)(a_d + c);
        #pragma unroll
        for (int i = 0; i < 4; ++i) {
            float sdot = acc[i][0] * asv.x + acc[i][1] * asv.y +
                         acc[i][2] * asv.z + acc[i][3] * asv.w;
            float ddot = acc[i][0] * adv.x + acc[i][1] * adv.y +
                         acc[i][2] * adv.z + acc[i][3] * adv.w;
            #pragma unroll
            for (int off = 1; off < 16; off <<= 1) {
                sdot += __shfl_xor(sdot, off);
                ddot += __shfl_xor(ddot, off);
            }
            const int r = row0 + (tr << 2) + i;
            if (tc == 0 && r < M) { hs[r] = sdot; hd[r] = ddot; }
        }
    }
}

// ---------------- CSR build --------------------------------------------------
__global__ __launch_bounds__(256) void edge_hist(
    const int* __restrict__ dst, int* __restrict__ cnt, int e)
{
    const int i = blockIdx.x * blockDim.x + threadIdx.x;
    if (i < e) atomicAdd(&cnt[dst[i]], 1);
}

// block: 256 threads, 1024 elements; exclusive scan chunk, emit block total
__global__ __launch_bounds__(256) void scan1(
    const int* __restrict__ cnt, int* __restrict__ out,
    int* __restrict__ bsum, int n)
{
    __shared__ int wsum[4];
    const int tid  = threadIdx.x;
    const int lane = tid & 63;
    const int w    = tid >> 6;
    const int base = blockIdx.x * 1024;
    int vals[4];
    int tsum = 0;
    #pragma unroll
    for (int i = 0; i < 4; ++i) {
        const int idx = base + tid * 4 + i;
        vals[i] = (idx < n) ? cnt[idx] : 0;
        tsum += vals[i];
    }
    int x = tsum;  // inclusive wave scan of per-thread sums
    #pragma unroll
    for (int off = 1; off < 64; off <<= 1) {
        const int y = __shfl_up(x, off);
        if (lane >= off) x += y;
    }
    if (lane == 63) wsum[w] = x;
    __syncthreads();
    int wofs = 0;
    for (int k = 0; k < w; ++k) wofs += wsum[k];
    int excl = wofs + x - tsum;
    #pragma unroll
    for (int i = 0; i < 4; ++i) {
        const int idx = base + tid * 4 + i;
        if (idx < n) out[idx] = excl;
        excl += vals[i];
    }
    if (tid == 255) bsum[blockIdx.x] = wofs + x;
}

// single block of 128 threads: exclusive scan of block sums in place
__global__ __launch_bounds__(128) void scan2(int* __restrict__ b, int nb)
{
    __shared__ int wtot[2];
    const int tid = threadIdx.x;
    const int lane = tid & 63;
    const int w = tid >> 6;
    const int v = (tid < nb) ? b[tid] : 0;
    int x = v;
    #pragma unroll
    for (int off = 1; off < 64; off <<= 1) {
        const int y = __shfl_up(x, off);
        if (lane >= off) x += y;
    }
    if (lane == 63) wtot[w] = x;
    __syncthreads();
    const int add = (w == 1) ? wtot[0] : 0;
    if (tid < nb) b[tid] = add + x - v;
}

__global__ __launch_bounds__(256) void scan3(
    int* __restrict__ out, const int* __restrict__ bsum, int n, int total)
{
    const int idx = blockIdx.x * blockDim.x + threadIdx.x;
    if (idx < n) out[idx] += bsum[idx >> 10];
    if (idx == 0) out[n] = total;
}

__global__ __launch_bounds__(256) void edge_scatter(
    const int* __restrict__ src, const int* __restrict__ dst,
    int* __restrict__ pos, int* __restrict__ ssrc, int e)
{
    const int i = blockIdx.x * blockDim.x + threadIdx.x;
    if (i < e) {
        const int p = atomicAdd(&pos[dst[i]], 1);
        ssrc[p] = src[i];
    }
}

// ---------------- gather aggregation ----------------------------------------
// One wave per node. Lanes split: 4 edge slots (sub = lane>>4) x 16 lanes,
// each lane holds float4 of features -> 4 (x2 unrolled) independent random
// gathers in flight per wave. Cross-slot reduce via shfl_xor(16/32).
// MODE 0: +bias, ReLU.   MODE 1: +bias, L2 row-normalize (final layer).
template <int MODE>
__global__ __launch_bounds__(256) void gat_agg(
    const float* __restrict__ hp, const float* __restrict__ hs,
    const float* __restrict__ hd, const int* __restrict__ offs,
    const int* __restrict__ ssrc, const float* __restrict__ bias,
    float* __restrict__ out, int n)
{
    const int wid  = (blockIdx.x * blockDim.x + threadIdx.x) >> 6;
    const int lane = threadIdx.x & 63;
    if (wid >= n) return;
    const int sub = lane >> 4;          // edge slot 0..3
    const int fl  = (lane & 15) << 2;   // feature offset (float4)

    const float hdi = hd[wid];
    float den = 0.f;
    float4 acc = make_float4(0.f, 0.f, 0.f, 0.f);

    // self-loop (reference appends loop edges) -> slot 0
    if (sub == 0) {
        float e = hs[wid] + hdi;
        e = (e > 0.f) ? e : NEG_SLOPE * e;
        const float ex = __expf(e);
        const float4 hv = *(const float4*)(hp + (size_t)wid * 64 + fl);
        den = ex;
        acc.x = ex * hv.x; acc.y = ex * hv.y;
        acc.z = ex * hv.z; acc.w = ex * hv.w;
    }

    const int start = offs[wid];
    const int end   = offs[wid + 1];
    #pragma unroll 2
    for (int j = start + sub; j < end; j += 4) {
        const int s = ssrc[j];
        float e2 = hs[s] + hdi;
        e2 = (e2 > 0.f) ? e2 : NEG_SLOPE * e2;
        const float ex2 = __expf(e2);
        const float4 hv = *(const float4*)(hp + (size_t)s * 64 + fl);
        den += ex2;
        acc.x = fmaf(ex2, hv.x, acc.x);
        acc.y = fmaf(ex2, hv.y, acc.y);
        acc.z = fmaf(ex2, hv.z, acc.z);
        acc.w = fmaf(ex2, hv.w, acc.w);
    }

    // reduce the 4 edge slots (lanes with same fl across groups)
    den   += __shfl_xor(den, 16);   den   += __shfl_xor(den, 32);
    acc.x += __shfl_xor(acc.x, 16); acc.x += __shfl_xor(acc.x, 32);
    acc.y += __shfl_xor(acc.y, 16); acc.y += __shfl_xor(acc.y, 32);
    acc.z += __shfl_xor(acc.z, 16); acc.z += __shfl_xor(acc.z, 32);
    acc.w += __shfl_xor(acc.w, 16); acc.w += __shfl_xor(acc.w, 32);

    const float4 bv = *(const float4*)(bias + fl);
    const float inv = 1.f / (den + 1e-16f);
    float4 v;
    v.x = acc.x * inv + bv.x;
    v.y = acc.y * inv + bv.y;
    v.z = acc.z * inv + bv.z;
    v.w = acc.w * inv + bv.w;

    if (MODE == 0) {
        v.x = fmaxf(v.x, 0.f); v.y = fmaxf(v.y, 0.f);
        v.z = fmaxf(v.z, 0.f); v.w = fmaxf(v.w, 0.f);
    } else {
        float sq = v.x * v.x + v.y * v.y + v.z * v.z + v.w * v.w;
        #pragma unroll
        for (int off = 1; off < 16; off <<= 1) sq += __shfl_xor(sq, off);
        const float s = 1.f / fmaxf(sqrtf(sq), 1e-12f);
        v.x *= s; v.y *= s; v.z *= s; v.w *= s;
    }
    if (sub == 0) *(float4*)(out + (size_t)wid * 64 + fl) = v;
}

// ---------------- launch -----------------------------------------------------
extern "C" void kernel_launch(void* const* d_in, const int* in_sizes, int n_in,
                              void* d_out, int out_size, void* d_ws, size_t ws_size,
                              hipStream_t stream)
{
    const float* x     = (const float*)d_in[0];
    const int*   src   = (const int*)d_in[1];
    const int*   dst   = (const int*)d_in[2];
    const float* lin_w = (const float*)d_in[3];
    const float* lin_b = (const float*)d_in[4];
    const float* w1  = (const float*)d_in[5];
    const float* a1s = (const float*)d_in[6];
    const float* a1d = (const float*)d_in[7];
    const float* b1  = (const float*)d_in[8];
    const float* w2  = (const float*)d_in[9];
    const float* a2s = (const float*)d_in[10];
    const float* a2d = (const float*)d_in[11];
    const float* b2  = (const float*)d_in[12];
    const float* w3  = (const float*)d_in[13];
    const float* a3s = (const float*)d_in[14];
    const float* a3d = (const float*)d_in[15];
    const float* b3  = (const float*)d_in[16];

    const int n = in_sizes[0] / 256;   // 100000 nodes
    const int E = in_sizes[1];         // 1280000 edges

    // workspace carve-up (256B aligned)
    char* wsp = (char*)d_ws;
    auto alloc = [&](size_t bytes) -> void* {
        void* p = (void*)wsp;
        wsp += (bytes + 255) & ~(size_t)255;
        return p;
    };
    float* bufA = (float*)alloc((size_t)n * 64 * sizeof(float));
    float* bufB = (float*)alloc((size_t)n * 64 * sizeof(float));
    float* hs   = (float*)alloc((size_t)n * sizeof(float));
    float* hd   = (float*)alloc((size_t)n * sizeof(float));
    int*   offs = (int*)alloc((size_t)(n + 1) * sizeof(int));
    int*   pos  = (int*)alloc((size_t)n * sizeof(int));   // doubles as cnt
    int*   bsum = (int*)alloc(1024 * sizeof(int));
    int*   ssrc = (int*)alloc((size_t)E * sizeof(int));

    const int edgeBlocks = (E + 255) / 256;
    const int nodeWaveBlocks = (n + 3) / 4;          // 4 waves / 256-thread block
    const int gemmBlocks = (n + 63) / 64;
    const int nScanBlocks = (n + 1023) / 1024;

    // ---- CSR build (reused by all 3 layers) ----
    hipMemsetAsync(pos, 0, (size_t)n * sizeof(int), stream);
    edge_hist<<<edgeBlocks, 256, 0, stream>>>(dst, pos, E);
    scan1<<<nScanBlocks, 256, 0, stream>>>(pos, offs, bsum, n);
    scan2<<<1, 128, 0, stream>>>(bsum, nScanBlocks);
    scan3<<<(n + 255) / 256, 256, 0, stream>>>(offs, bsum, n, E);
    hipMemcpyAsync(pos, offs, (size_t)n * sizeof(int), hipMemcpyDeviceToDevice, stream);
    edge_scatter<<<edgeBlocks, 256, 0, stream>>>(src, dst, pos, ssrc, E);

    // ---- feature_pre linear: h0 = x @ lin_w + lin_b -> bufA ----
    gemm64<false><<<gemmBlocks, 256, 0, stream>>>(x, lin_w, lin_b, bufA, n, 256,
                                                  nullptr, nullptr, nullptr, nullptr);

    // ---- layer 1 ----
    gemm64<true><<<gemmBlocks, 256, 0, stream>>>(bufA, w1, nullptr, bufB, n, 64,
                                                 a1s, a1d, hs, hd);
    gat_agg<0><<<nodeWaveBlocks, 256, 0, stream>>>(bufB, hs, hd, offs, ssrc, b1, bufA, n);

    // ---- layer 2 ----
    gemm64<true><<<gemmBlocks, 256, 0, stream>>>(bufA, w2, nullptr, bufB, n, 64,
                                                 a2s, a2d, hs, hd);
    gat_agg<0><<<nodeWaveBlocks, 256, 0, stream>>>(bufB, hs, hd, offs, ssrc, b2, bufA, n);

    // ---- layer 3 + normalize -> d_out ----
    gemm64<true><<<gemmBlocks, 256, 0, stream>>>(bufA, w3, nullptr, bufB, n, 64,
                                                 a3s, a3d, hs, hd);
    gat_agg<1><<<nodeWaveBlocks, 256, 0, stream>>>(bufB, hs, hd, offs, ssrc, b3,
                                                   (float*)d_out, n);
}

// Round 3
// 539.883 us; speedup vs baseline: 1.5356x; 1.0708x over previous
//
#include <hip/hip_runtime.h>

// GAT 3-layer on MI355X.
//   CSR build: hist -> scan -> bucket-partition -> per-bucket scatter
//     (two-phase scatter keeps each ssrc region single-writer-block ->
//      L2 line merging -> no 16x HBM write amplification)
//   h0 = x @ lin_w + lin_b               [fp32 tiled GEMM]
//   per layer: h' = h @ w (attn dots fused in epilogue); gather-aggregate
//   final layer fuses bias + L2 row normalize.

constexpr float NEG_SLOPE = 0.2f;
#define BKT_SHIFT 9                // 512 nodes per bucket
#define BKT_N     512
#define PCHUNK    4096             // edges staged per partition block

// ---------------- GEMM: C[M x 64] = A[M x K] @ B[K x 64] (+ optional bias) ---
// DOTS: also emit hs[r] = C_row . a_s, hd[r] = C_row . a_d (pre-bias h').
template <bool DOTS>
__global__ __launch_bounds__(256) void gemm64(
    const float* __restrict__ A, const float* __restrict__ B,
    const float* __restrict__ bias, float* __restrict__ C, int M, int K,
    const float* __restrict__ a_s, const float* __restrict__ a_d,
    float* __restrict__ hs, float* __restrict__ hd)
{
    __shared__ float As[16][64];   // As[k][r] (transposed for float4 row reads)
    __shared__ float Bs[16][64];   // Bs[k][c]
    const int tid  = threadIdx.x;
    const int row0 = blockIdx.x * 64;
    const int tr = tid >> 4;              // 0..15 -> rows 4*tr..4*tr+3
    const int tc = tid & 15;              // 0..15 -> cols 4*tc..4*tc+3
    const int ar = tid >> 2;              // 0..63 (row in A tile)
    const int ak = (tid & 3) << 2;        // k chunk (float4)
    const int bk = tid >> 4;              // 0..15 (row in B tile)
    const int bc = (tid & 15) << 2;       // col chunk (float4)

    float acc[4][4] = {};

    for (int k0 = 0; k0 < K; k0 += 16) {
        float4 av = make_float4(0.f, 0.f, 0.f, 0.f);
        const int arow = row0 + ar;
        if (arow < M) av = *(const float4*)(A + (size_t)arow * K + k0 + ak);
        const float4 bv = *(const float4*)(B + (size_t)(k0 + bk) * 64 + bc);
        __syncthreads();
        As[ak + 0][ar] = av.x;
        As[ak + 1][ar] = av.y;
        As[ak + 2][ar] = av.z;
        As[ak + 3][ar] = av.w;
        *(float4*)(&Bs[bk][bc]) = bv;
        __syncthreads();
        #pragma unroll
        for (int kk = 0; kk < 16; ++kk) {
            const float4 a4 = *(const float4*)(&As[kk][tr << 2]);
            const float4 b4 = *(const float4*)(&Bs[kk][tc << 2]);
            const float aa[4] = {a4.x, a4.y, a4.z, a4.w};
            const float bb[4] = {b4.x, b4.y, b4.z, b4.w};
            #pragma unroll
            for (int i = 0; i < 4; ++i)
                #pragma unroll
                for (int j = 0; j < 4; ++j)
                    acc[i][j] = fmaf(aa[i], bb[j], acc[i][j]);
        }
    }

    const int c = tc << 2;
    float b0 = 0.f, b1 = 0.f, b2 = 0.f, b3 = 0.f;
    if (bias) { b0 = bias[c]; b1 = bias[c + 1]; b2 = bias[c + 2]; b3 = bias[c + 3]; }
    #pragma unroll
    for (int i = 0; i < 4; ++i) {
        const int r = row0 + (tr << 2) + i;
        if (r < M) {
            float4 v;
            v.x = acc[i][0] + b0;
            v.y = acc[i][1] + b1;
            v.z = acc[i][2] + b2;
            v.w = acc[i][3] + b3;
            *(float4*)(C + (size_t)r * 64 + c) = v;
        }
    }

    if (DOTS) {
        const float4 asv = *(const float4*)(a_s + c);
        const float4 adv = *(const float4*)(a_d + c);
        #pragma unroll
        for (int i = 0; i < 4; ++i) {
            float sdot = acc[i][0] * asv.x + acc[i][1] * asv.y +
                         acc[i][2] * asv.z + acc[i][3] * asv.w;
            float ddot = acc[i][0] * adv.x + acc[i][1] * adv.y +
                         acc[i][2] * adv.z + acc[i][3] * adv.w;
            #pragma unroll
            for (int off = 1; off < 16; off <<= 1) {
                sdot += __shfl_xor(sdot, off);
                ddot += __shfl_xor(ddot, off);
            }
            const int r = row0 + (tr << 2) + i;
            if (tc == 0 && r < M) { hs[r] = sdot; hd[r] = ddot; }
        }
    }
}

// ---------------- CSR build --------------------------------------------------
__global__ __launch_bounds__(256) void edge_hist(
    const int* __restrict__ dst, int* __restrict__ cnt, int e)
{
    const int i = blockIdx.x * blockDim.x + threadIdx.x;
    if (i < e) atomicAdd(&cnt[dst[i]], 1);
}

__global__ __launch_bounds__(256) void scan1(
    const int* __restrict__ cnt, int* __restrict__ out,
    int* __restrict__ bsum, int n)
{
    __shared__ int wsum[4];
    const int tid  = threadIdx.x;
    const int lane = tid & 63;
    const int w    = tid >> 6;
    const int base = blockIdx.x * 1024;
    int vals[4];
    int tsum = 0;
    #pragma unroll
    for (int i = 0; i < 4; ++i) {
        const int idx = base + tid * 4 + i;
        vals[i] = (idx < n) ? cnt[idx] : 0;
        tsum += vals[i];
    }
    int x = tsum;
    #pragma unroll
    for (int off = 1; off < 64; off <<= 1) {
        const int y = __shfl_up(x, off);
        if (lane >= off) x += y;
    }
    if (lane == 63) wsum[w] = x;
    __syncthreads();
    int wofs = 0;
    for (int k = 0; k < w; ++k) wofs += wsum[k];
    int excl = wofs + x - tsum;
    #pragma unroll
    for (int i = 0; i < 4; ++i) {
        const int idx = base + tid * 4 + i;
        if (idx < n) out[idx] = excl;
        excl += vals[i];
    }
    if (tid == 255) bsum[blockIdx.x] = wofs + x;
}

__global__ __launch_bounds__(128) void scan2(int* __restrict__ b, int nb)
{
    __shared__ int wtot[2];
    const int tid = threadIdx.x;
    const int lane = tid & 63;
    const int w = tid >> 6;
    const int v = (tid < nb) ? b[tid] : 0;
    int x = v;
    #pragma unroll
    for (int off = 1; off < 64; off <<= 1) {
        const int y = __shfl_up(x, off);
        if (lane >= off) x += y;
    }
    if (lane == 63) wtot[w] = x;
    __syncthreads();
    const int add = (w == 1) ? wtot[0] : 0;
    if (tid < nb) b[tid] = add + x - v;
}

__global__ __launch_bounds__(256) void scan3(
    int* __restrict__ out, const int* __restrict__ bsum, int n, int total)
{
    const int idx = blockIdx.x * blockDim.x + threadIdx.x;
    if (idx < n) out[idx] += bsum[idx >> 10];
    if (idx == 0) out[n] = total;
}

// gcursor[b] = start of bucket b's edge region (CSR-aligned: offs[b*512])
__global__ __launch_bounds__(256) void cursor_init(
    const int* __restrict__ offs, int* __restrict__ gcur, int n, int nb)
{
    const int b = threadIdx.x;
    if (b < nb) gcur[b] = offs[min(b << BKT_SHIFT, n)];
}

// Phase 1: bucket edges by dst>>9 into CSR-aligned regions, coalesced runs.
__global__ __launch_bounds__(256) void edge_partition(
    const int* __restrict__ src, const int* __restrict__ dst,
    int* __restrict__ gcursor, int2* __restrict__ pairs, int e, int nb)
{
    __shared__ int2 stage[PCHUNK];
    __shared__ int lcnt[256];
    __shared__ int lstart[256];
    __shared__ int lfill[256];
    __shared__ int gbase[256];
    __shared__ int wsum[4];

    const int tid  = threadIdx.x;
    const int lane = tid & 63;
    const int w    = tid >> 6;
    const int base = blockIdx.x * PCHUNK;
    const int cnt_here = min(PCHUNK, e - base);

    lcnt[tid] = 0; lfill[tid] = 0;
    __syncthreads();

    int2 items[PCHUNK / 256];
    int nmine = 0;
    for (int i = tid; i < cnt_here; i += 256) {
        int2 it; it.x = src[base + i]; it.y = dst[base + i];
        items[nmine++] = it;
        atomicAdd(&lcnt[it.y >> BKT_SHIFT], 1);
    }
    __syncthreads();

    // exclusive scan of lcnt[256] -> lstart
    const int v = lcnt[tid];
    int x = v;
    #pragma unroll
    for (int off = 1; off < 64; off <<= 1) {
        const int y = __shfl_up(x, off);
        if (lane >= off) x += y;
    }
    if (lane == 63) wsum[w] = x;
    __syncthreads();
    int carry = 0;
    for (int k = 0; k < w; ++k) carry += wsum[k];
    lstart[tid] = carry + x - v;
    // reserve global runs (one atomic per non-empty bucket)
    if (tid < nb && v > 0) gbase[tid] = atomicAdd(&gcursor[tid], v);
    __syncthreads();

    // bucket-major staging in LDS
    for (int k = 0; k < nmine; ++k) {
        const int b = items[k].y >> BKT_SHIFT;
        const int p = lstart[b] + atomicAdd(&lfill[b], 1);
        stage[p] = items[k];
    }
    __syncthreads();

    // contiguous write-out per bucket run
    for (int s = tid; s < cnt_here; s += 256) {
        const int2 it = stage[s];
        const int b = it.y >> BKT_SHIFT;
        pairs[gbase[b] + (s - lstart[b])] = it;
    }
}

// Phase 2: one block per bucket; per-node cursors in LDS; writes confined
// to this block's contiguous ssrc region (single-XCD line merging).
__global__ __launch_bounds__(256) void bucket_scatter(
    const int2* __restrict__ pairs, const int* __restrict__ offs,
    int* __restrict__ ssrc, int n)
{
    __shared__ int pos[BKT_N];
    const int node0 = blockIdx.x << BKT_SHIFT;
    const int node1 = min(n, node0 + BKT_N);
    const int tid = threadIdx.x;
    for (int i = tid; i < node1 - node0; i += 256) pos[i] = offs[node0 + i];
    __syncthreads();
    const int e0 = offs[node0];
    const int e1 = offs[node1];
    for (int j = e0 + tid; j < e1; j += 256) {
        const int2 it = pairs[j];
        const int p = atomicAdd(&pos[it.y - node0], 1);
        ssrc[p] = it.x;
    }
}

// ---------------- gather aggregation ----------------------------------------
// One wave per node; 4 edge slots x 16 lanes (float4/lane).
// MODE 0: +bias, ReLU.   MODE 1: +bias, L2 row-normalize (final layer).
template <int MODE>
__global__ __launch_bounds__(256) void gat_agg(
    const float* __restrict__ hp, const float* __restrict__ hs,
    const float* __restrict__ hd, const int* __restrict__ offs,
    const int* __restrict__ ssrc, const float* __restrict__ bias,
    float* __restrict__ out, int n)
{
    const int wid  = (blockIdx.x * blockDim.x + threadIdx.x) >> 6;
    const int lane = threadIdx.x & 63;
    if (wid >= n) return;
    const int sub = lane >> 4;          // edge slot 0..3
    const int fl  = (lane & 15) << 2;   // feature offset (float4)

    const float hdi = hd[wid];
    float den = 0.f;
    float4 acc = make_float4(0.f, 0.f, 0.f, 0.f);

    if (sub == 0) {   // self-loop
        float e = hs[wid] + hdi;
        e = (e > 0.f) ? e : NEG_SLOPE * e;
        const float ex = __expf(e);
        const float4 hv = *(const float4*)(hp + (size_t)wid * 64 + fl);
        den = ex;
        acc.x = ex * hv.x; acc.y = ex * hv.y;
        acc.z = ex * hv.z; acc.w = ex * hv.w;
    }

    const int start = offs[wid];
    const int end   = offs[wid + 1];
    #pragma unroll 2
    for (int j = start + sub; j < end; j += 4) {
        const int s = ssrc[j];
        float e2 = hs[s] + hdi;
        e2 = (e2 > 0.f) ? e2 : NEG_SLOPE * e2;
        const float ex2 = __expf(e2);
        const float4 hv = *(const float4*)(hp + (size_t)s * 64 + fl);
        den += ex2;
        acc.x = fmaf(ex2, hv.x, acc.x);
        acc.y = fmaf(ex2, hv.y, acc.y);
        acc.z = fmaf(ex2, hv.z, acc.z);
        acc.w = fmaf(ex2, hv.w, acc.w);
    }

    den   += __shfl_xor(den, 16);   den   += __shfl_xor(den, 32);
    acc.x += __shfl_xor(acc.x, 16); acc.x += __shfl_xor(acc.x, 32);
    acc.y += __shfl_xor(acc.y, 16); acc.y += __shfl_xor(acc.y, 32);
    acc.z += __shfl_xor(acc.z, 16); acc.z += __shfl_xor(acc.z, 32);
    acc.w += __shfl_xor(acc.w, 16); acc.w += __shfl_xor(acc.w, 32);

    const float4 bv = *(const float4*)(bias + fl);
    const float inv = 1.f / (den + 1e-16f);
    float4 v;
    v.x = acc.x * inv + bv.x;
    v.y = acc.y * inv + bv.y;
    v.z = acc.z * inv + bv.z;
    v.w = acc.w * inv + bv.w;

    if (MODE == 0) {
        v.x = fmaxf(v.x, 0.f); v.y = fmaxf(v.y, 0.f);
        v.z = fmaxf(v.z, 0.f); v.w = fmaxf(v.w, 0.f);
    } else {
        float sq = v.x * v.x + v.y * v.y + v.z * v.z + v.w * v.w;
        #pragma unroll
        for (int off = 1; off < 16; off <<= 1) sq += __shfl_xor(sq, off);
        const float s = 1.f / fmaxf(sqrtf(sq), 1e-12f);
        v.x *= s; v.y *= s; v.z *= s; v.w *= s;
    }
    if (sub == 0) *(float4*)(out + (size_t)wid * 64 + fl) = v;
}

// ---------------- launch -----------------------------------------------------
extern "C" void kernel_launch(void* const* d_in, const int* in_sizes, int n_in,
                              void* d_out, int out_size, void* d_ws, size_t ws_size,
                              hipStream_t stream)
{
    const float* x     = (const float*)d_in[0];
    const int*   src   = (const int*)d_in[1];
    const int*   dst   = (const int*)d_in[2];
    const float* lin_w = (const float*)d_in[3];
    const float* lin_b = (const float*)d_in[4];
    const float* w1  = (const float*)d_in[5];
    const float* a1s = (const float*)d_in[6];
    const float* a1d = (const float*)d_in[7];
    const float* b1  = (const float*)d_in[8];
    const float* w2  = (const float*)d_in[9];
    const float* a2s = (const float*)d_in[10];
    const float* a2d = (const float*)d_in[11];
    const float* b2  = (const float*)d_in[12];
    const float* w3  = (const float*)d_in[13];
    const float* a3s = (const float*)d_in[14];
    const float* a3d = (const float*)d_in[15];
    const float* b3  = (const float*)d_in[16];

    const int n = in_sizes[0] / 256;   // 100000 nodes
    const int E = in_sizes[1];         // 1280000 edges
    const int nb = (n + BKT_N - 1) >> BKT_SHIFT;   // 196 buckets

    // workspace carve-up (256B aligned)
    char* wsp = (char*)d_ws;
    auto alloc = [&](size_t bytes) -> void* {
        void* p = (void*)wsp;
        wsp += (bytes + 255) & ~(size_t)255;
        return p;
    };
    float* bufA = (float*)alloc((size_t)n * 64 * sizeof(float));
    float* bufB = (float*)alloc((size_t)n * 64 * sizeof(float));
    float* hs   = (float*)alloc((size_t)n * sizeof(float));
    float* hd   = (float*)alloc((size_t)n * sizeof(float));
    int*   offs = (int*)alloc((size_t)(n + 1) * sizeof(int));
    int*   cnt  = (int*)alloc((size_t)n * sizeof(int));
    int*   bsum = (int*)alloc(1024 * sizeof(int));
    int*   gcur = (int*)alloc(256 * sizeof(int));
    int*   ssrc = (int*)alloc((size_t)E * sizeof(int));
    int2*  pairs = (int2*)bufB;   // alias: only live during CSR build

    const int edgeBlocks = (E + 255) / 256;
    const int nodeWaveBlocks = (n + 3) / 4;          // 4 waves / 256-thread block
    const int gemmBlocks = (n + 63) / 64;
    const int nScanBlocks = (n + 1023) / 1024;
    const int partBlocks = (E + PCHUNK - 1) / PCHUNK;

    // ---- CSR build (reused by all 3 layers) ----
    hipMemsetAsync(cnt, 0, (size_t)n * sizeof(int), stream);
    edge_hist<<<edgeBlocks, 256, 0, stream>>>(dst, cnt, E);
    scan1<<<nScanBlocks, 256, 0, stream>>>(cnt, offs, bsum, n);
    scan2<<<1, 128, 0, stream>>>(bsum, nScanBlocks);
    scan3<<<(n + 255) / 256, 256, 0, stream>>>(offs, bsum, n, E);
    cursor_init<<<1, 256, 0, stream>>>(offs, gcur, n, nb);
    edge_partition<<<partBlocks, 256, 0, stream>>>(src, dst, gcur, pairs, E, nb);
    bucket_scatter<<<nb, 256, 0, stream>>>(pairs, offs, ssrc, n);

    // ---- feature_pre linear: h0 = x @ lin_w + lin_b -> bufA ----
    gemm64<false><<<gemmBlocks, 256, 0, stream>>>(x, lin_w, lin_b, bufA, n, 256,
                                                  nullptr, nullptr, nullptr, nullptr);

    // ---- layer 1 ----
    gemm64<true><<<gemmBlocks, 256, 0, stream>>>(bufA, w1, nullptr, bufB, n, 64,
                                                 a1s, a1d, hs, hd);
    gat_agg<0><<<nodeWaveBlocks, 256, 0, stream>>>(bufB, hs, hd, offs, ssrc, b1, bufA, n);

    // ---- layer 2 ----
    gemm64<true><<<gemmBlocks, 256, 0, stream>>>(bufA, w2, nullptr, bufB, n, 64,
                                                 a2s, a2d, hs, hd);
    gat_agg<0><<<nodeWaveBlocks, 256, 0, stream>>>(bufB, hs, hd, offs, ssrc, b2, bufA, n);

    // ---- layer 3 + normalize -> d_out ----
    gemm64<true><<<gemmBlocks, 256, 0, stream>>>(bufA, w3, nullptr, bufB, n, 64,
                                                 a3s, a3d, hs, hd);
    gat_agg<1><<<nodeWaveBlocks, 256, 0, stream>>>(bufB, hs, hd, offs, ssrc, b3,
                                                   (float*)d_out, n);
}

// Round 4
// 502.615 us; speedup vs baseline: 1.6495x; 1.0741x over previous
//
#include <hip/hip_runtime.h>

// GAT 3-layer on MI355X — bf16/MFMA pipeline.
//   CSR build: hist -> scan -> bucket-partition -> per-bucket scatter
//   prep: weights -> bf16 transposed
//   h0 = bf16(x @ lin_w + lin_b)          [MFMA 16x16x32, fp32->bf16 in-reg]
//   per layer: h' = h @ w (MFMA, attn dots fused); gather-aggregate (bf16 rows)
//   final layer: bias + L2 row normalize -> fp32 d_out.

constexpr float NEG_SLOPE = 0.2f;
#define BKT_SHIFT 9                // 512 nodes per bucket
#define BKT_N     512
#define PCHUNK    4096             // edges staged per partition block

typedef __attribute__((ext_vector_type(8))) short bf16x8;
typedef __attribute__((ext_vector_type(4))) float f32x4;

__device__ inline ushort f2bf(float x) {
    union { float f; uint u; } v; v.f = x;
    return (ushort)((v.u + 0x7FFFu + ((v.u >> 16) & 1u)) >> 16);
}
__device__ inline void bf2f(uint u, float& lo, float& hi) {
    union { uint u; float f; } a, b;
    a.u = u << 16; b.u = u & 0xFFFF0000u;
    lo = a.f; hi = b.f;
}
__device__ inline uint pk(float a, float b) {
    return (uint)f2bf(a) | ((uint)f2bf(b) << 16);
}

// ---------------- weight prep: bf16 transpose ---------------------------------
__global__ __launch_bounds__(256) void prep_w(
    const float* __restrict__ lw, const float* __restrict__ w1,
    const float* __restrict__ w2, const float* __restrict__ w3,
    ushort* __restrict__ lwT, ushort* __restrict__ w1T,
    ushort* __restrict__ w2T, ushort* __restrict__ w3T)
{
    const int i = blockIdx.x * 256 + threadIdx.x;
    if (i < 64 * 256) {                 // lwT[n][k] = lw[k][n], K=256
        const int nn = i >> 8, k = i & 255;
        lwT[i] = f2bf(lw[k * 64 + nn]);
    } else {
        const int j = i - 64 * 256;
        if (j < 4096) {                 // wT[n][k] = w[k][n], K=64
            const int nn = j >> 6, k = j & 63;
            w1T[j] = f2bf(w1[k * 64 + nn]);
            w2T[j] = f2bf(w2[k * 64 + nn]);
            w3T[j] = f2bf(w3[k * 64 + nn]);
        }
    }
}

// ---------------- GEMM1: h0 = bf16(x[M x 256] @ lin_w + lin_b) ----------------
// One wave per 16 rows. A from fp32 global (cvt in-reg), B = lwT bf16 [64][256].
__global__ __launch_bounds__(256) void gemm_pre(
    const float* __restrict__ x, const ushort* __restrict__ lwT,
    const float* __restrict__ bias, ushort* __restrict__ C, int M)
{
    __shared__ __align__(16) ushort ctile[4][16][64];
    const int tid = threadIdx.x;
    const int w = tid >> 6, lane = tid & 63;
    const int rw0 = (blockIdx.x * 4 + w) * 16;
    if (rw0 >= M) return;
    const int c = lane & 15, q = lane >> 4;

    f32x4 acc[4];
    #pragma unroll
    for (int t = 0; t < 4; ++t) acc[t] = (f32x4){0.f, 0.f, 0.f, 0.f};

    const float* ap = x + (size_t)(rw0 + c) * 256 + q * 8;
    #pragma unroll
    for (int s = 0; s < 8; ++s) {
        const float4 p0 = *(const float4*)(ap + s * 32);
        const float4 p1 = *(const float4*)(ap + s * 32 + 4);
        bf16x8 af;
        af[0] = (short)f2bf(p0.x); af[1] = (short)f2bf(p0.y);
        af[2] = (short)f2bf(p0.z); af[3] = (short)f2bf(p0.w);
        af[4] = (short)f2bf(p1.x); af[5] = (short)f2bf(p1.y);
        af[6] = (short)f2bf(p1.z); af[7] = (short)f2bf(p1.w);
        #pragma unroll
        for (int t = 0; t < 4; ++t) {
            const bf16x8 bf = *(const bf16x8*)(lwT + (size_t)(t * 16 + c) * 256 + s * 32 + q * 8);
            acc[t] = __builtin_amdgcn_mfma_f32_16x16x32_bf16(af, bf, acc[t], 0, 0, 0);
        }
    }

    // bias + bf16 store via per-wave LDS transpose (C/D: row=q*4+reg, col=16t+c)
    #pragma unroll
    for (int t = 0; t < 4; ++t) {
        const float bv = bias[t * 16 + c];
        #pragma unroll
        for (int r = 0; r < 4; ++r)
            ctile[w][q * 4 + r][t * 16 + c] = f2bf(acc[t][r] + bv);
    }
    const int row = lane >> 2, eo = (lane & 3) * 16;
    const uint4 v0 = *(const uint4*)(&ctile[w][row][eo]);
    const uint4 v1 = *(const uint4*)(&ctile[w][row][eo + 8]);
    *(uint4*)(C + (size_t)(rw0 + row) * 64 + eo)     = v0;
    *(uint4*)(C + (size_t)(rw0 + row) * 64 + eo + 8) = v1;
}

// ---------------- layer GEMM: C = A[M x 64] @ w, + attn dots ------------------
// A bf16 row-major, WT bf16 [n][k]. Emits C bf16 and hs/hd fp32 (pre-bias).
__global__ __launch_bounds__(256) void gemm_layer(
    const ushort* __restrict__ A, const ushort* __restrict__ WT,
    const float* __restrict__ a_s, const float* __restrict__ a_d,
    ushort* __restrict__ C, float* __restrict__ hs, float* __restrict__ hd, int M)
{
    __shared__ __align__(16) ushort ctile[4][16][64];
    const int tid = threadIdx.x;
    const int w = tid >> 6, lane = tid & 63;
    const int rw0 = (blockIdx.x * 4 + w) * 16;
    if (rw0 >= M) return;
    const int c = lane & 15, q = lane >> 4;

    const ushort* ap = A + (size_t)(rw0 + c) * 64 + q * 8;
    const bf16x8 a0 = *(const bf16x8*)(ap);
    const bf16x8 a1 = *(const bf16x8*)(ap + 32);

    f32x4 acc[4];
    #pragma unroll
    for (int t = 0; t < 4; ++t) {
        const ushort* bp = WT + (size_t)(t * 16 + c) * 64 + q * 8;
        const bf16x8 b0 = *(const bf16x8*)(bp);
        const bf16x8 b1 = *(const bf16x8*)(bp + 32);
        f32x4 a = (f32x4){0.f, 0.f, 0.f, 0.f};
        a = __builtin_amdgcn_mfma_f32_16x16x32_bf16(a0, b0, a, 0, 0, 0);
        a = __builtin_amdgcn_mfma_f32_16x16x32_bf16(a1, b1, a, 0, 0, 0);
        acc[t] = a;
    }

    // attn dots: hs[r] = sum_n C[r][n]*a_s[n]; lane holds cols {16t+c}
    float ps[4] = {0.f, 0.f, 0.f, 0.f}, pd[4] = {0.f, 0.f, 0.f, 0.f};
    #pragma unroll
    for (int t = 0; t < 4; ++t) {
        const float as = a_s[t * 16 + c], ad = a_d[t * 16 + c];
        #pragma unroll
        for (int r = 0; r < 4; ++r) {
            ps[r] = fmaf(acc[t][r], as, ps[r]);
            pd[r] = fmaf(acc[t][r], ad, pd[r]);
        }
    }
    #pragma unroll
    for (int r = 0; r < 4; ++r) {
        #pragma unroll
        for (int off = 1; off < 16; off <<= 1) {
            ps[r] += __shfl_xor(ps[r], off);
            pd[r] += __shfl_xor(pd[r], off);
        }
    }
    if (c == 0) {
        #pragma unroll
        for (int r = 0; r < 4; ++r) {
            hs[rw0 + q * 4 + r] = ps[r];
            hd[rw0 + q * 4 + r] = pd[r];
        }
    }

    // bf16 store via per-wave LDS transpose
    #pragma unroll
    for (int t = 0; t < 4; ++t)
        #pragma unroll
        for (int r = 0; r < 4; ++r)
            ctile[w][q * 4 + r][t * 16 + c] = f2bf(acc[t][r]);
    const int row = lane >> 2, eo = (lane & 3) * 16;
    const uint4 v0 = *(const uint4*)(&ctile[w][row][eo]);
    const uint4 v1 = *(const uint4*)(&ctile[w][row][eo + 8]);
    *(uint4*)(C + (size_t)(rw0 + row) * 64 + eo)     = v0;
    *(uint4*)(C + (size_t)(rw0 + row) * 64 + eo + 8) = v1;
}

// ---------------- CSR build --------------------------------------------------
__global__ __launch_bounds__(256) void edge_hist(
    const int* __restrict__ dst, int* __restrict__ cnt, int e)
{
    const int i = blockIdx.x * blockDim.x + threadIdx.x;
    if (i < e) atomicAdd(&cnt[dst[i]], 1);
}

__global__ __launch_bounds__(256) void scan1(
    const int* __restrict__ cnt, int* __restrict__ out,
    int* __restrict__ bsum, int n)
{
    __shared__ int wsum[4];
    const int tid  = threadIdx.x;
    const int lane = tid & 63;
    const int w    = tid >> 6;
    const int base = blockIdx.x * 1024;
    int vals[4];
    int tsum = 0;
    #pragma unroll
    for (int i = 0; i < 4; ++i) {
        const int idx = base + tid * 4 + i;
        vals[i] = (idx < n) ? cnt[idx] : 0;
        tsum += vals[i];
    }
    int x = tsum;
    #pragma unroll
    for (int off = 1; off < 64; off <<= 1) {
        const int y = __shfl_up(x, off);
        if (lane >= off) x += y;
    }
    if (lane == 63) wsum[w] = x;
    __syncthreads();
    int wofs = 0;
    for (int k = 0; k < w; ++k) wofs += wsum[k];
    int excl = wofs + x - tsum;
    #pragma unroll
    for (int i = 0; i < 4; ++i) {
        const int idx = base + tid * 4 + i;
        if (idx < n) out[idx] = excl;
        excl += vals[i];
    }
    if (tid == 255) bsum[blockIdx.x] = wofs + x;
}

__global__ __launch_bounds__(128) void scan2(int* __restrict__ b, int nb)
{
    __shared__ int wtot[2];
    const int tid = threadIdx.x;
    const int lane = tid & 63;
    const int w = tid >> 6;
    const int v = (tid < nb) ? b[tid] : 0;
    int x = v;
    #pragma unroll
    for (int off = 1; off < 64; off <<= 1) {
        const int y = __shfl_up(x, off);
        if (lane >= off) x += y;
    }
    if (lane == 63) wtot[w] = x;
    __syncthreads();
    const int add = (w == 1) ? wtot[0] : 0;
    if (tid < nb) b[tid] = add + x - v;
}

__global__ __launch_bounds__(256) void scan3(
    int* __restrict__ out, const int* __restrict__ bsum, int n, int total)
{
    const int idx = blockIdx.x * blockDim.x + threadIdx.x;
    if (idx < n) out[idx] += bsum[idx >> 10];
    if (idx == 0) out[n] = total;
}

__global__ __launch_bounds__(256) void cursor_init(
    const int* __restrict__ offs, int* __restrict__ gcur, int n, int nb)
{
    const int b = threadIdx.x;
    if (b < nb) gcur[b] = offs[min(b << BKT_SHIFT, n)];
}

__global__ __launch_bounds__(256) void edge_partition(
    const int* __restrict__ src, const int* __restrict__ dst,
    int* __restrict__ gcursor, int2* __restrict__ pairs, int e, int nb)
{
    __shared__ int2 stage[PCHUNK];
    __shared__ int lcnt[256];
    __shared__ int lstart[256];
    __shared__ int lfill[256];
    __shared__ int gbase[256];
    __shared__ int wsum[4];

    const int tid  = threadIdx.x;
    const int lane = tid & 63;
    const int w    = tid >> 6;
    const int base = blockIdx.x * PCHUNK;
    const int cnt_here = min(PCHUNK, e - base);

    lcnt[tid] = 0; lfill[tid] = 0;
    __syncthreads();

    int2 items[PCHUNK / 256];
    int nmine = 0;
    for (int i = tid; i < cnt_here; i += 256) {
        int2 it; it.x = src[base + i]; it.y = dst[base + i];
        items[nmine++] = it;
        atomicAdd(&lcnt[it.y >> BKT_SHIFT], 1);
    }
    __syncthreads();

    const int v = lcnt[tid];
    int x = v;
    #pragma unroll
    for (int off = 1; off < 64; off <<= 1) {
        const int y = __shfl_up(x, off);
        if (lane >= off) x += y;
    }
    if (lane == 63) wsum[w] = x;
    __syncthreads();
    int carry = 0;
    for (int k = 0; k < w; ++k) carry += wsum[k];
    lstart[tid] = carry + x - v;
    if (tid < nb && v > 0) gbase[tid] = atomicAdd(&gcursor[tid], v);
    __syncthreads();

    for (int k = 0; k < nmine; ++k) {
        const int b = items[k].y >> BKT_SHIFT;
        const int p = lstart[b] + atomicAdd(&lfill[b], 1);
        stage[p] = items[k];
    }
    __syncthreads();

    for (int s = tid; s < cnt_here; s += 256) {
        const int2 it = stage[s];
        const int b = it.y >> BKT_SHIFT;
        pairs[gbase[b] + (s - lstart[b])] = it;
    }
}

__global__ __launch_bounds__(256) void bucket_scatter(
    const int2* __restrict__ pairs, const int* __restrict__ offs,
    int* __restrict__ ssrc, int n)
{
    __shared__ int pos[BKT_N];
    const int node0 = blockIdx.x << BKT_SHIFT;
    const int node1 = min(n, node0 + BKT_N);
    const int tid = threadIdx.x;
    for (int i = tid; i < node1 - node0; i += 256) pos[i] = offs[node0 + i];
    __syncthreads();
    const int e0 = offs[node0];
    const int e1 = offs[node1];
    for (int j = e0 + tid; j < e1; j += 256) {
        const int2 it = pairs[j];
        const int p = atomicAdd(&pos[it.y - node0], 1);
        ssrc[p] = it.x;
    }
}

// ---------------- gather aggregation (bf16 rows) -----------------------------
// One wave per node; 8 edge slots x 8 lanes (16 B = 8 bf16 per lane).
// MODE 0: +bias, ReLU -> bf16 out.  MODE 1: +bias, L2 normalize -> fp32 out.
template <int MODE>
__global__ __launch_bounds__(256) void gat_agg(
    const ushort* __restrict__ hp, const float* __restrict__ hs,
    const float* __restrict__ hd, const int* __restrict__ offs,
    const int* __restrict__ ssrc, const float* __restrict__ bias,
    void* __restrict__ outv, int n)
{
    const int wid  = (blockIdx.x * blockDim.x + threadIdx.x) >> 6;
    const int lane = threadIdx.x & 63;
    if (wid >= n) return;
    const int sub = lane >> 3;          // edge slot 0..7
    const int f0  = (lane & 7) * 8;     // feature offset (8 bf16)

    const float hdi = hd[wid];
    float den = 0.f;
    float acc[8] = {};

    if (sub == 0) {   // self-loop
        float e = hs[wid] + hdi;
        e = (e > 0.f) ? e : NEG_SLOPE * e;
        const float ex = __expf(e);
        const uint4 t = *(const uint4*)(hp + (size_t)wid * 64 + f0);
        float f[8];
        bf2f(t.x, f[0], f[1]); bf2f(t.y, f[2], f[3]);
        bf2f(t.z, f[4], f[5]); bf2f(t.w, f[6], f[7]);
        den = ex;
        #pragma unroll
        for (int i = 0; i < 8; ++i) acc[i] = ex * f[i];
    }

    const int start = offs[wid];
    const int end   = offs[wid + 1];
    #pragma unroll 2
    for (int j = start + sub; j < end; j += 8) {
        const int s = ssrc[j];
        float e2 = hs[s] + hdi;
        e2 = (e2 > 0.f) ? e2 : NEG_SLOPE * e2;
        const float ex2 = __expf(e2);
        const uint4 t = *(const uint4*)(hp + (size_t)s * 64 + f0);
        float f[8];
        bf2f(t.x, f[0], f[1]); bf2f(t.y, f[2], f[3]);
        bf2f(t.z, f[4], f[5]); bf2f(t.w, f[6], f[7]);
        den += ex2;
        #pragma unroll
        for (int i = 0; i < 8; ++i) acc[i] = fmaf(ex2, f[i], acc[i]);
    }

    // reduce the 8 edge slots (lanes with same f0)
    #pragma unroll
    for (int off = 8; off < 64; off <<= 1) {
        den += __shfl_xor(den, off);
        #pragma unroll
        for (int i = 0; i < 8; ++i) acc[i] += __shfl_xor(acc[i], off);
    }

    const float4 bv0 = *(const float4*)(bias + f0);
    const float4 bv1 = *(const float4*)(bias + f0 + 4);
    const float bb[8] = {bv0.x, bv0.y, bv0.z, bv0.w, bv1.x, bv1.y, bv1.z, bv1.w};
    const float inv = 1.f / (den + 1e-16f);
    float v[8];
    #pragma unroll
    for (int i = 0; i < 8; ++i) v[i] = acc[i] * inv + bb[i];

    if (MODE == 0) {
        #pragma unroll
        for (int i = 0; i < 8; ++i) v[i] = fmaxf(v[i], 0.f);
        if (sub == 0) {
            uint4 o;
            o.x = pk(v[0], v[1]); o.y = pk(v[2], v[3]);
            o.z = pk(v[4], v[5]); o.w = pk(v[6], v[7]);
            *(uint4*)((ushort*)outv + (size_t)wid * 64 + f0) = o;
        }
    } else {
        float sq = 0.f;
        #pragma unroll
        for (int i = 0; i < 8; ++i) sq += v[i] * v[i];
        #pragma unroll
        for (int off = 1; off < 8; off <<= 1) sq += __shfl_xor(sq, off);
        const float s = 1.f / fmaxf(sqrtf(sq), 1e-12f);
        if (sub == 0) {
            float* op = (float*)outv + (size_t)wid * 64 + f0;
            float4 o0, o1;
            o0.x = v[0] * s; o0.y = v[1] * s; o0.z = v[2] * s; o0.w = v[3] * s;
            o1.x = v[4] * s; o1.y = v[5] * s; o1.z = v[6] * s; o1.w = v[7] * s;
            *(float4*)(op)     = o0;
            *(float4*)(op + 4) = o1;
        }
    }
}

// ---------------- launch -----------------------------------------------------
extern "C" void kernel_launch(void* const* d_in, const int* in_sizes, int n_in,
                              void* d_out, int out_size, void* d_ws, size_t ws_size,
                              hipStream_t stream)
{
    const float* x     = (const float*)d_in[0];
    const int*   src   = (const int*)d_in[1];
    const int*   dst   = (const int*)d_in[2];
    const float* lin_w = (const float*)d_in[3];
    const float* lin_b = (const float*)d_in[4];
    const float* w1  = (const float*)d_in[5];
    const float* a1s = (const float*)d_in[6];
    const float* a1d = (const float*)d_in[7];
    const float* b1  = (const float*)d_in[8];
    const float* w2  = (const float*)d_in[9];
    const float* a2s = (const float*)d_in[10];
    const float* a2d = (const float*)d_in[11];
    const float* b2  = (const float*)d_in[12];
    const float* w3  = (const float*)d_in[13];
    const float* a3s = (const float*)d_in[14];
    const float* a3d = (const float*)d_in[15];
    const float* b3  = (const float*)d_in[16];

    const int n = in_sizes[0] / 256;   // 100000 nodes
    const int E = in_sizes[1];         // 1280000 edges
    const int nb = (n + BKT_N - 1) >> BKT_SHIFT;

    char* wsp = (char*)d_ws;
    auto alloc = [&](size_t bytes) -> void* {
        void* p = (void*)wsp;
        wsp += (bytes + 255) & ~(size_t)255;
        return p;
    };
    ushort* bufA = (ushort*)alloc((size_t)n * 64 * sizeof(ushort));   // bf16 h
    ushort* bufB = (ushort*)alloc((size_t)n * 64 * sizeof(ushort));   // bf16 h'
    float*  hs   = (float*)alloc((size_t)n * sizeof(float));
    float*  hd   = (float*)alloc((size_t)n * sizeof(float));
    int*    offs = (int*)alloc((size_t)(n + 1) * sizeof(int));
    int*    cnt  = (int*)alloc((size_t)n * sizeof(int));
    int*    bsum = (int*)alloc(1024 * sizeof(int));
    int*    gcur = (int*)alloc(256 * sizeof(int));
    int*    ssrc = (int*)alloc((size_t)E * sizeof(int));
    int2*   pairs = (int2*)alloc((size_t)E * sizeof(int2));
    ushort* lwT = (ushort*)alloc(64 * 256 * sizeof(ushort));
    ushort* w1T = (ushort*)alloc(64 * 64 * sizeof(ushort));
    ushort* w2T = (ushort*)alloc(64 * 64 * sizeof(ushort));
    ushort* w3T = (ushort*)alloc(64 * 64 * sizeof(ushort));

    const int edgeBlocks = (E + 255) / 256;
    const int nodeWaveBlocks = (n + 3) / 4;
    const int gemmBlocks = (n + 63) / 64;
    const int nScanBlocks = (n + 1023) / 1024;
    const int partBlocks = (E + PCHUNK - 1) / PCHUNK;

    // ---- weight prep + CSR build ----
    prep_w<<<(64 * 256 + 4096 + 255) / 256, 256, 0, stream>>>(
        lin_w, w1, w2, w3, lwT, w1T, w2T, w3T);
    hipMemsetAsync(cnt, 0, (size_t)n * sizeof(int), stream);
    edge_hist<<<edgeBlocks, 256, 0, stream>>>(dst, cnt, E);
    scan1<<<nScanBlocks, 256, 0, stream>>>(cnt, offs, bsum, n);
    scan2<<<1, 128, 0, stream>>>(bsum, nScanBlocks);
    scan3<<<(n + 255) / 256, 256, 0, stream>>>(offs, bsum, n, E);
    cursor_init<<<1, 256, 0, stream>>>(offs, gcur, n, nb);
    edge_partition<<<partBlocks, 256, 0, stream>>>(src, dst, gcur, pairs, E, nb);
    bucket_scatter<<<nb, 256, 0, stream>>>(pairs, offs, ssrc, n);

    // ---- h0 = bf16(x @ lin_w + lin_b) ----
    gemm_pre<<<gemmBlocks, 256, 0, stream>>>(x, lwT, lin_b, bufA, n);

    // ---- layer 1 ----
    gemm_layer<<<gemmBlocks, 256, 0, stream>>>(bufA, w1T, a1s, a1d, bufB, hs, hd, n);
    gat_agg<0><<<nodeWaveBlocks, 256, 0, stream>>>(bufB, hs, hd, offs, ssrc, b1, bufA, n);

    // ---- layer 2 ----
    gemm_layer<<<gemmBlocks, 256, 0, stream>>>(bufA, w2T, a2s, a2d, bufB, hs, hd, n);
    gat_agg<0><<<nodeWaveBlocks, 256, 0, stream>>>(bufB, hs, hd, offs, ssrc, b2, bufA, n);

    // ---- layer 3 + normalize -> d_out ----
    gemm_layer<<<gemmBlocks, 256, 0, stream>>>(bufA, w3T, a3s, a3d, bufB, hs, hd, n);
    gat_agg<1><<<nodeWaveBlocks, 256, 0, stream>>>(bufB, hs, hd, offs, ssrc, b3,
                                                   d_out, n);
}

// Round 5
// 490.189 us; speedup vs baseline: 1.6913x; 1.0253x over previous
//
#include <hip/hip_runtime.h>

// GAT 3-layer on MI355X — bf16/MFMA pipeline.
//   CSR build: hist -> scan -> bucket-partition -> per-bucket scatter
//   prep: weights -> bf16 transposed
//   h0 = bf16(x @ lin_w + lin_b)          [MFMA 16x16x32, fp32->bf16 in-reg]
//   per layer: h' = h @ w (MFMA, attn dots fused); gather-aggregate (bf16 rows)
//   final layer: bias + L2 row normalize -> fp32 d_out.
// R4: edge_partition restructured as 2-pass over global (no per-thread
// staging array -> no scratch spill; PCHUNK 2048 -> 20.5 KB LDS).

constexpr float NEG_SLOPE = 0.2f;
#define BKT_SHIFT 9                // 512 nodes per bucket
#define BKT_N     512
#define PCHUNK    2048             // edges staged per partition block

typedef __attribute__((ext_vector_type(8))) short bf16x8;
typedef __attribute__((ext_vector_type(4))) float f32x4;

__device__ inline ushort f2bf(float x) {
    union { float f; uint u; } v; v.f = x;
    return (ushort)((v.u + 0x7FFFu + ((v.u >> 16) & 1u)) >> 16);
}
__device__ inline void bf2f(uint u, float& lo, float& hi) {
    union { uint u; float f; } a, b;
    a.u = u << 16; b.u = u & 0xFFFF0000u;
    lo = a.f; hi = b.f;
}
__device__ inline uint pk(float a, float b) {
    return (uint)f2bf(a) | ((uint)f2bf(b) << 16);
}

// ---------------- weight prep: bf16 transpose ---------------------------------
__global__ __launch_bounds__(256) void prep_w(
    const float* __restrict__ lw, const float* __restrict__ w1,
    const float* __restrict__ w2, const float* __restrict__ w3,
    ushort* __restrict__ lwT, ushort* __restrict__ w1T,
    ushort* __restrict__ w2T, ushort* __restrict__ w3T)
{
    const int i = blockIdx.x * 256 + threadIdx.x;
    if (i < 64 * 256) {                 // lwT[n][k] = lw[k][n], K=256
        const int nn = i >> 8, k = i & 255;
        lwT[i] = f2bf(lw[k * 64 + nn]);
    } else {
        const int j = i - 64 * 256;
        if (j < 4096) {                 // wT[n][k] = w[k][n], K=64
            const int nn = j >> 6, k = j & 63;
            w1T[j] = f2bf(w1[k * 64 + nn]);
            w2T[j] = f2bf(w2[k * 64 + nn]);
            w3T[j] = f2bf(w3[k * 64 + nn]);
        }
    }
}

// ---------------- GEMM1: h0 = bf16(x[M x 256] @ lin_w + lin_b) ----------------
// One wave per 16 rows. A from fp32 global (cvt in-reg), B = lwT bf16 [64][256].
__global__ __launch_bounds__(256) void gemm_pre(
    const float* __restrict__ x, const ushort* __restrict__ lwT,
    const float* __restrict__ bias, ushort* __restrict__ C, int M)
{
    __shared__ __align__(16) ushort ctile[4][16][64];
    const int tid = threadIdx.x;
    const int w = tid >> 6, lane = tid & 63;
    const int rw0 = (blockIdx.x * 4 + w) * 16;
    if (rw0 >= M) return;
    const int c = lane & 15, q = lane >> 4;

    f32x4 acc[4];
    #pragma unroll
    for (int t = 0; t < 4; ++t) acc[t] = (f32x4){0.f, 0.f, 0.f, 0.f};

    const float* ap = x + (size_t)(rw0 + c) * 256 + q * 8;
    #pragma unroll
    for (int s = 0; s < 8; ++s) {
        const float4 p0 = *(const float4*)(ap + s * 32);
        const float4 p1 = *(const float4*)(ap + s * 32 + 4);
        bf16x8 af;
        af[0] = (short)f2bf(p0.x); af[1] = (short)f2bf(p0.y);
        af[2] = (short)f2bf(p0.z); af[3] = (short)f2bf(p0.w);
        af[4] = (short)f2bf(p1.x); af[5] = (short)f2bf(p1.y);
        af[6] = (short)f2bf(p1.z); af[7] = (short)f2bf(p1.w);
        #pragma unroll
        for (int t = 0; t < 4; ++t) {
            const bf16x8 bf = *(const bf16x8*)(lwT + (size_t)(t * 16 + c) * 256 + s * 32 + q * 8);
            acc[t] = __builtin_amdgcn_mfma_f32_16x16x32_bf16(af, bf, acc[t], 0, 0, 0);
        }
    }

    // bias + bf16 store via per-wave LDS transpose (C/D: row=q*4+reg, col=16t+c)
    #pragma unroll
    for (int t = 0; t < 4; ++t) {
        const float bv = bias[t * 16 + c];
        #pragma unroll
        for (int r = 0; r < 4; ++r)
            ctile[w][q * 4 + r][t * 16 + c] = f2bf(acc[t][r] + bv);
    }
    const int row = lane >> 2, eo = (lane & 3) * 16;
    const uint4 v0 = *(const uint4*)(&ctile[w][row][eo]);
    const uint4 v1 = *(const uint4*)(&ctile[w][row][eo + 8]);
    *(uint4*)(C + (size_t)(rw0 + row) * 64 + eo)     = v0;
    *(uint4*)(C + (size_t)(rw0 + row) * 64 + eo + 8) = v1;
}

// ---------------- layer GEMM: C = A[M x 64] @ w, + attn dots ------------------
// A bf16 row-major, WT bf16 [n][k]. Emits C bf16 and hs/hd fp32 (pre-bias).
__global__ __launch_bounds__(256) void gemm_layer(
    const ushort* __restrict__ A, const ushort* __restrict__ WT,
    const float* __restrict__ a_s, const float* __restrict__ a_d,
    ushort* __restrict__ C, float* __restrict__ hs, float* __restrict__ hd, int M)
{
    __shared__ __align__(16) ushort ctile[4][16][64];
    const int tid = threadIdx.x;
    const int w = tid >> 6, lane = tid & 63;
    const int rw0 = (blockIdx.x * 4 + w) * 16;
    if (rw0 >= M) return;
    const int c = lane & 15, q = lane >> 4;

    const ushort* ap = A + (size_t)(rw0 + c) * 64 + q * 8;
    const bf16x8 a0 = *(const bf16x8*)(ap);
    const bf16x8 a1 = *(const bf16x8*)(ap + 32);

    f32x4 acc[4];
    #pragma unroll
    for (int t = 0; t < 4; ++t) {
        const ushort* bp = WT + (size_t)(t * 16 + c) * 64 + q * 8;
        const bf16x8 b0 = *(const bf16x8*)(bp);
        const bf16x8 b1 = *(const bf16x8*)(bp + 32);
        f32x4 a = (f32x4){0.f, 0.f, 0.f, 0.f};
        a = __builtin_amdgcn_mfma_f32_16x16x32_bf16(a0, b0, a, 0, 0, 0);
        a = __builtin_amdgcn_mfma_f32_16x16x32_bf16(a1, b1, a, 0, 0, 0);
        acc[t] = a;
    }

    // attn dots: hs[r] = sum_n C[r][n]*a_s[n]; lane holds cols {16t+c}
    float ps[4] = {0.f, 0.f, 0.f, 0.f}, pd[4] = {0.f, 0.f, 0.f, 0.f};
    #pragma unroll
    for (int t = 0; t < 4; ++t) {
        const float as = a_s[t * 16 + c], ad = a_d[t * 16 + c];
        #pragma unroll
        for (int r = 0; r < 4; ++r) {
            ps[r] = fmaf(acc[t][r], as, ps[r]);
            pd[r] = fmaf(acc[t][r], ad, pd[r]);
        }
    }
    #pragma unroll
    for (int r = 0; r < 4; ++r) {
        #pragma unroll
        for (int off = 1; off < 16; off <<= 1) {
            ps[r] += __shfl_xor(ps[r], off);
            pd[r] += __shfl_xor(pd[r], off);
        }
    }
    if (c == 0) {
        #pragma unroll
        for (int r = 0; r < 4; ++r) {
            hs[rw0 + q * 4 + r] = ps[r];
            hd[rw0 + q * 4 + r] = pd[r];
        }
    }

    // bf16 store via per-wave LDS transpose
    #pragma unroll
    for (int t = 0; t < 4; ++t)
        #pragma unroll
        for (int r = 0; r < 4; ++r)
            ctile[w][q * 4 + r][t * 16 + c] = f2bf(acc[t][r]);
    const int row = lane >> 2, eo = (lane & 3) * 16;
    const uint4 v0 = *(const uint4*)(&ctile[w][row][eo]);
    const uint4 v1 = *(const uint4*)(&ctile[w][row][eo + 8]);
    *(uint4*)(C + (size_t)(rw0 + row) * 64 + eo)     = v0;
    *(uint4*)(C + (size_t)(rw0 + row) * 64 + eo + 8) = v1;
}

// ---------------- CSR build --------------------------------------------------
__global__ __launch_bounds__(256) void edge_hist(
    const int* __restrict__ dst, int* __restrict__ cnt, int e)
{
    const int i = blockIdx.x * blockDim.x + threadIdx.x;
    if (i < e) atomicAdd(&cnt[dst[i]], 1);
}

__global__ __launch_bounds__(256) void scan1(
    const int* __restrict__ cnt, int* __restrict__ out,
    int* __restrict__ bsum, int n)
{
    __shared__ int wsum[4];
    const int tid  = threadIdx.x;
    const int lane = tid & 63;
    const int w    = tid >> 6;
    const int base = blockIdx.x * 1024;
    int vals[4];
    int tsum = 0;
    #pragma unroll
    for (int i = 0; i < 4; ++i) {
        const int idx = base + tid * 4 + i;
        vals[i] = (idx < n) ? cnt[idx] : 0;
        tsum += vals[i];
    }
    int x = tsum;
    #pragma unroll
    for (int off = 1; off < 64; off <<= 1) {
        const int y = __shfl_up(x, off);
        if (lane >= off) x += y;
    }
    if (lane == 63) wsum[w] = x;
    __syncthreads();
    int wofs = 0;
    for (int k = 0; k < w; ++k) wofs += wsum[k];
    int excl = wofs + x - tsum;
    #pragma unroll
    for (int i = 0; i < 4; ++i) {
        const int idx = base + tid * 4 + i;
        if (idx < n) out[idx] = excl;
        excl += vals[i];
    }
    if (tid == 255) bsum[blockIdx.x] = wofs + x;
}

__global__ __launch_bounds__(128) void scan2(int* __restrict__ b, int nb)
{
    __shared__ int wtot[2];
    const int tid = threadIdx.x;
    const int lane = tid & 63;
    const int w = tid >> 6;
    const int v = (tid < nb) ? b[tid] : 0;
    int x = v;
    #pragma unroll
    for (int off = 1; off < 64; off <<= 1) {
        const int y = __shfl_up(x, off);
        if (lane >= off) x += y;
    }
    if (lane == 63) wtot[w] = x;
    __syncthreads();
    const int add = (w == 1) ? wtot[0] : 0;
    if (tid < nb) b[tid] = add + x - v;
}

__global__ __launch_bounds__(256) void scan3(
    int* __restrict__ out, const int* __restrict__ bsum, int n, int total)
{
    const int idx = blockIdx.x * blockDim.x + threadIdx.x;
    if (idx < n) out[idx] += bsum[idx >> 10];
    if (idx == 0) out[n] = total;
}

__global__ __launch_bounds__(256) void cursor_init(
    const int* __restrict__ offs, int* __restrict__ gcur, int n, int nb)
{
    const int b = threadIdx.x;
    if (b < nb) gcur[b] = offs[min(b << BKT_SHIFT, n)];
}

// Phase 1: bucket edges by dst>>9 into CSR-aligned regions, coalesced runs.
// 2-pass over the global chunk (2nd read is L2-hot) — no per-thread staging
// array, no scratch spill.
__global__ __launch_bounds__(256) void edge_partition(
    const int* __restrict__ src, const int* __restrict__ dst,
    int* __restrict__ gcursor, int2* __restrict__ pairs, int e, int nb)
{
    __shared__ int2 stage[PCHUNK];
    __shared__ int lcnt[256];
    __shared__ int lstart[256];
    __shared__ int lfill[256];
    __shared__ int gbase[256];
    __shared__ int wsum[4];

    const int tid  = threadIdx.x;
    const int lane = tid & 63;
    const int w    = tid >> 6;
    const int base = blockIdx.x * PCHUNK;
    const int cnt_here = min(PCHUNK, e - base);

    lcnt[tid] = 0; lfill[tid] = 0;
    __syncthreads();

    // pass 1: bucket histogram
    for (int i = tid; i < cnt_here; i += 256)
        atomicAdd(&lcnt[dst[base + i] >> BKT_SHIFT], 1);
    __syncthreads();

    // exclusive scan of lcnt[256] -> lstart; reserve global runs
    const int v = lcnt[tid];
    int x = v;
    #pragma unroll
    for (int off = 1; off < 64; off <<= 1) {
        const int y = __shfl_up(x, off);
        if (lane >= off) x += y;
    }
    if (lane == 63) wsum[w] = x;
    __syncthreads();
    int carry = 0;
    for (int k = 0; k < w; ++k) carry += wsum[k];
    lstart[tid] = carry + x - v;
    if (tid < nb && v > 0) gbase[tid] = atomicAdd(&gcursor[tid], v);
    __syncthreads();

    // pass 2: re-read (L2-hot) and stage bucket-major in LDS
    for (int i = tid; i < cnt_here; i += 256) {
        int2 it; it.x = src[base + i]; it.y = dst[base + i];
        const int b = it.y >> BKT_SHIFT;
        const int p = lstart[b] + atomicAdd(&lfill[b], 1);
        stage[p] = it;
    }
    __syncthreads();

    // contiguous write-out per bucket run
    for (int s = tid; s < cnt_here; s += 256) {
        const int2 it = stage[s];
        const int b = it.y >> BKT_SHIFT;
        pairs[gbase[b] + (s - lstart[b])] = it;
    }
}

// Phase 2: one block per bucket; per-node cursors in LDS; writes confined
// to this block's contiguous ssrc region (single-XCD line merging).
__global__ __launch_bounds__(256) void bucket_scatter(
    const int2* __restrict__ pairs, const int* __restrict__ offs,
    int* __restrict__ ssrc, int n)
{
    __shared__ int pos[BKT_N];
    const int node0 = blockIdx.x << BKT_SHIFT;
    const int node1 = min(n, node0 + BKT_N);
    const int tid = threadIdx.x;
    for (int i = tid; i < node1 - node0; i += 256) pos[i] = offs[node0 + i];
    __syncthreads();
    const int e0 = offs[node0];
    const int e1 = offs[node1];
    for (int j = e0 + tid; j < e1; j += 256) {
        const int2 it = pairs[j];
        const int p = atomicAdd(&pos[it.y - node0], 1);
        ssrc[p] = it.x;
    }
}

// ---------------- gather aggregation (bf16 rows) -----------------------------
// One wave per node; 8 edge slots x 8 lanes (16 B = 8 bf16 per lane).
// MODE 0: +bias, ReLU -> bf16 out.  MODE 1: +bias, L2 normalize -> fp32 out.
template <int MODE>
__global__ __launch_bounds__(256) void gat_agg(
    const ushort* __restrict__ hp, const float* __restrict__ hs,
    const float* __restrict__ hd, const int* __restrict__ offs,
    const int* __restrict__ ssrc, const float* __restrict__ bias,
    void* __restrict__ outv, int n)
{
    const int wid  = (blockIdx.x * blockDim.x + threadIdx.x) >> 6;
    const int lane = threadIdx.x & 63;
    if (wid >= n) return;
    const int sub = lane >> 3;          // edge slot 0..7
    const int f0  = (lane & 7) * 8;     // feature offset (8 bf16)

    const float hdi = hd[wid];
    float den = 0.f;
    float acc[8] = {};

    if (sub == 0) {   // self-loop
        float e = hs[wid] + hdi;
        e = (e > 0.f) ? e : NEG_SLOPE * e;
        const float ex = __expf(e);
        const uint4 t = *(const uint4*)(hp + (size_t)wid * 64 + f0);
        float f[8];
        bf2f(t.x, f[0], f[1]); bf2f(t.y, f[2], f[3]);
        bf2f(t.z, f[4], f[5]); bf2f(t.w, f[6], f[7]);
        den = ex;
        #pragma unroll
        for (int i = 0; i < 8; ++i) acc[i] = ex * f[i];
    }

    const int start = offs[wid];
    const int end   = offs[wid + 1];
    #pragma unroll 2
    for (int j = start + sub; j < end; j += 8) {
        const int s = ssrc[j];
        float e2 = hs[s] + hdi;
        e2 = (e2 > 0.f) ? e2 : NEG_SLOPE * e2;
        const float ex2 = __expf(e2);
        const uint4 t = *(const uint4*)(hp + (size_t)s * 64 + f0);
        float f[8];
        bf2f(t.x, f[0], f[1]); bf2f(t.y, f[2], f[3]);
        bf2f(t.z, f[4], f[5]); bf2f(t.w, f[6], f[7]);
        den += ex2;
        #pragma unroll
        for (int i = 0; i < 8; ++i) acc[i] = fmaf(ex2, f[i], acc[i]);
    }

    // reduce the 8 edge slots (lanes with same f0)
    #pragma unroll
    for (int off = 8; off < 64; off <<= 1) {
        den += __shfl_xor(den, off);
        #pragma unroll
        for (int i = 0; i < 8; ++i) acc[i] += __shfl_xor(acc[i], off);
    }

    const float4 bv0 = *(const float4*)(bias + f0);
    const float4 bv1 = *(const float4*)(bias + f0 + 4);
    const float bb[8] = {bv0.x, bv0.y, bv0.z, bv0.w, bv1.x, bv1.y, bv1.z, bv1.w};
    const float inv = 1.f / (den + 1e-16f);
    float v[8];
    #pragma unroll
    for (int i = 0; i < 8; ++i) v[i] = acc[i] * inv + bb[i];

    if (MODE == 0) {
        #pragma unroll
        for (int i = 0; i < 8; ++i) v[i] = fmaxf(v[i], 0.f);
        if (sub == 0) {
            uint4 o;
            o.x = pk(v[0], v[1]); o.y = pk(v[2], v[3]);
            o.z = pk(v[4], v[5]); o.w = pk(v[6], v[7]);
            *(uint4*)((ushort*)outv + (size_t)wid * 64 + f0) = o;
        }
    } else {
        float sq = 0.f;
        #pragma unroll
        for (int i = 0; i < 8; ++i) sq += v[i] * v[i];
        #pragma unroll
        for (int off = 1; off < 8; off <<= 1) sq += __shfl_xor(sq, off);
        const float s = 1.f / fmaxf(sqrtf(sq), 1e-12f);
        if (sub == 0) {
            float* op = (float*)outv + (size_t)wid * 64 + f0;
            float4 o0, o1;
            o0.x = v[0] * s; o0.y = v[1] * s; o0.z = v[2] * s; o0.w = v[3] * s;
            o1.x = v[4] * s; o1.y = v[5] * s; o1.z = v[6] * s; o1.w = v[7] * s;
            *(float4*)(op)     = o0;
            *(float4*)(op + 4) = o1;
        }
    }
}

// ---------------- launch -----------------------------------------------------
extern "C" void kernel_launch(void* const* d_in, const int* in_sizes, int n_in,
                              void* d_out, int out_size, void* d_ws, size_t ws_size,
                              hipStream_t stream)
{
    const float* x     = (const float*)d_in[0];
    const int*   src   = (const int*)d_in[1];
    const int*   dst   = (const int*)d_in[2];
    const float* lin_w = (const float*)d_in[3];
    const float* lin_b = (const float*)d_in[4];
    const float* w1  = (const float*)d_in[5];
    const float* a1s = (const float*)d_in[6];
    const float* a1d = (const float*)d_in[7];
    const float* b1  = (const float*)d_in[8];
    const float* w2  = (const float*)d_in[9];
    const float* a2s = (const float*)d_in[10];
    const float* a2d = (const float*)d_in[11];
    const float* b2  = (const float*)d_in[12];
    const float* w3  = (const float*)d_in[13];
    const float* a3s = (const float*)d_in[14];
    const float* a3d = (const float*)d_in[15];
    const float* b3  = (const float*)d_in[16];

    const int n = in_sizes[0] / 256;   // 100000 nodes
    const int E = in_sizes[1];         // 1280000 edges
    const int nb = (n + BKT_N - 1) >> BKT_SHIFT;

    char* wsp = (char*)d_ws;
    auto alloc = [&](size_t bytes) -> void* {
        void* p = (void*)wsp;
        wsp += (bytes + 255) & ~(size_t)255;
        return p;
    };
    ushort* bufA = (ushort*)alloc((size_t)n * 64 * sizeof(ushort));   // bf16 h
    ushort* bufB = (ushort*)alloc((size_t)n * 64 * sizeof(ushort));   // bf16 h'
    float*  hs   = (float*)alloc((size_t)n * sizeof(float));
    float*  hd   = (float*)alloc((size_t)n * sizeof(float));
    int*    offs = (int*)alloc((size_t)(n + 1) * sizeof(int));
    int*    cnt  = (int*)alloc((size_t)n * sizeof(int));
    int*    bsum = (int*)alloc(1024 * sizeof(int));
    int*    gcur = (int*)alloc(256 * sizeof(int));
    int*    ssrc = (int*)alloc((size_t)E * sizeof(int));
    int2*   pairs = (int2*)alloc((size_t)E * sizeof(int2));
    ushort* lwT = (ushort*)alloc(64 * 256 * sizeof(ushort));
    ushort* w1T = (ushort*)alloc(64 * 64 * sizeof(ushort));
    ushort* w2T = (ushort*)alloc(64 * 64 * sizeof(ushort));
    ushort* w3T = (ushort*)alloc(64 * 64 * sizeof(ushort));

    const int edgeBlocks = (E + 255) / 256;
    const int nodeWaveBlocks = (n + 3) / 4;
    const int gemmBlocks = (n + 63) / 64;
    const int nScanBlocks = (n + 1023) / 1024;
    const int partBlocks = (E + PCHUNK - 1) / PCHUNK;

    // ---- weight prep + CSR build ----
    prep_w<<<(64 * 256 + 4096 + 255) / 256, 256, 0, stream>>>(
        lin_w, w1, w2, w3, lwT, w1T, w2T, w3T);
    hipMemsetAsync(cnt, 0, (size_t)n * sizeof(int), stream);
    edge_hist<<<edgeBlocks, 256, 0, stream>>>(dst, cnt, E);
    scan1<<<nScanBlocks, 256, 0, stream>>>(cnt, offs, bsum, n);
    scan2<<<1, 128, 0, stream>>>(bsum, nScanBlocks);
    scan3<<<(n + 255) / 256, 256, 0, stream>>>(offs, bsum, n, E);
    cursor_init<<<1, 256, 0, stream>>>(offs, gcur, n, nb);
    edge_partition<<<partBlocks, 256, 0, stream>>>(src, dst, gcur, pairs, E, nb);
    bucket_scatter<<<nb, 256, 0, stream>>>(pairs, offs, ssrc, n);

    // ---- h0 = bf16(x @ lin_w + lin_b) ----
    gemm_pre<<<gemmBlocks, 256, 0, stream>>>(x, lwT, lin_b, bufA, n);

    // ---- layer 1 ----
    gemm_layer<<<gemmBlocks, 256, 0, stream>>>(bufA, w1T, a1s, a1d, bufB, hs, hd, n);
    gat_agg<0><<<nodeWaveBlocks, 256, 0, stream>>>(bufB, hs, hd, offs, ssrc, b1, bufA, n);

    // ---- layer 2 ----
    gemm_layer<<<gemmBlocks, 256, 0, stream>>>(bufA, w2T, a2s, a2d, bufB, hs, hd, n);
    gat_agg<0><<<nodeWaveBlocks, 256, 0, stream>>>(bufB, hs, hd, offs, ssrc, b2, bufA, n);

    // ---- layer 3 + normalize -> d_out ----
    gemm_layer<<<gemmBlocks, 256, 0, stream>>>(bufA, w3T, a3s, a3d, bufB, hs, hd, n);
    gat_agg<1><<<nodeWaveBlocks, 256, 0, stream>>>(bufB, hs, hd, offs, ssrc, b3,
                                                   d_out, n);
}

// Round 6
// 489.645 us; speedup vs baseline: 1.6932x; 1.0011x over previous
//
#include <hip/hip_runtime.h>

// GAT 3-layer on MI355X — bf16/MFMA pipeline.
//   CSR build: hist -> scan -> bucket-partition -> per-bucket scatter
//   prep: weights -> bf16 transposed
//   h0 = bf16(x @ lin_w + lin_b)          [MFMA 16x16x32, fp32->bf16 in-reg]
//   per layer: h' = h @ w (MFMA, attn dots fused); gather-aggregate (bf16 rows)
//   final layer: bias + L2 row normalize -> fp32 d_out.
// R5: gemm_pre hoists all 16 x-loads per lane ahead of the MFMA chain
// (VGPR 28 -> ~110) to fix the 3-deep-MLP latency bound seen in R4 counters.

constexpr float NEG_SLOPE = 0.2f;
#define BKT_SHIFT 9                // 512 nodes per bucket
#define BKT_N     512
#define PCHUNK    2048             // edges staged per partition block

typedef __attribute__((ext_vector_type(8))) short bf16x8;
typedef __attribute__((ext_vector_type(4))) float f32x4;

__device__ inline ushort f2bf(float x) {
    union { float f; uint u; } v; v.f = x;
    return (ushort)((v.u + 0x7FFFu + ((v.u >> 16) & 1u)) >> 16);
}
__device__ inline void bf2f(uint u, float& lo, float& hi) {
    union { uint u; float f; } a, b;
    a.u = u << 16; b.u = u & 0xFFFF0000u;
    lo = a.f; hi = b.f;
}
__device__ inline uint pk(float a, float b) {
    return (uint)f2bf(a) | ((uint)f2bf(b) << 16);
}

// ---------------- weight prep: bf16 transpose ---------------------------------
__global__ __launch_bounds__(256) void prep_w(
    const float* __restrict__ lw, const float* __restrict__ w1,
    const float* __restrict__ w2, const float* __restrict__ w3,
    ushort* __restrict__ lwT, ushort* __restrict__ w1T,
    ushort* __restrict__ w2T, ushort* __restrict__ w3T)
{
    const int i = blockIdx.x * 256 + threadIdx.x;
    if (i < 64 * 256) {                 // lwT[n][k] = lw[k][n], K=256
        const int nn = i >> 8, k = i & 255;
        lwT[i] = f2bf(lw[k * 64 + nn]);
    } else {
        const int j = i - 64 * 256;
        if (j < 4096) {                 // wT[n][k] = w[k][n], K=64
            const int nn = j >> 6, k = j & 63;
            w1T[j] = f2bf(w1[k * 64 + nn]);
            w2T[j] = f2bf(w2[k * 64 + nn]);
            w3T[j] = f2bf(w3[k * 64 + nn]);
        }
    }
}

// ---------------- GEMM1: h0 = bf16(x[M x 256] @ lin_w + lin_b) ----------------
// One wave per 16 rows. All 16 A-loads issued up front (16 outstanding/lane),
// then cvt+MFMA. B = lwT bf16 [64][256] stays L1/L2-hot.
__global__ __launch_bounds__(256) void gemm_pre(
    const float* __restrict__ x, const ushort* __restrict__ lwT,
    const float* __restrict__ bias, ushort* __restrict__ C, int M)
{
    __shared__ __align__(16) ushort ctile[4][16][64];
    const int tid = threadIdx.x;
    const int w = tid >> 6, lane = tid & 63;
    const int rw0 = (blockIdx.x * 4 + w) * 16;
    if (rw0 >= M) return;
    const int c = lane & 15, q = lane >> 4;

    // issue all A loads back-to-back (16 global_load_dwordx4 in flight)
    const float* ap = x + (size_t)(rw0 + c) * 256 + q * 8;
    float4 pv[16];
    #pragma unroll
    for (int s = 0; s < 8; ++s) {
        pv[2 * s]     = *(const float4*)(ap + s * 32);
        pv[2 * s + 1] = *(const float4*)(ap + s * 32 + 4);
    }

    f32x4 acc[4];
    #pragma unroll
    for (int t = 0; t < 4; ++t) acc[t] = (f32x4){0.f, 0.f, 0.f, 0.f};

    #pragma unroll
    for (int s = 0; s < 8; ++s) {
        const float4 p0 = pv[2 * s];
        const float4 p1 = pv[2 * s + 1];
        bf16x8 af;
        af[0] = (short)f2bf(p0.x); af[1] = (short)f2bf(p0.y);
        af[2] = (short)f2bf(p0.z); af[3] = (short)f2bf(p0.w);
        af[4] = (short)f2bf(p1.x); af[5] = (short)f2bf(p1.y);
        af[6] = (short)f2bf(p1.z); af[7] = (short)f2bf(p1.w);
        #pragma unroll
        for (int t = 0; t < 4; ++t) {
            const bf16x8 bf = *(const bf16x8*)(lwT + (size_t)(t * 16 + c) * 256 + s * 32 + q * 8);
            acc[t] = __builtin_amdgcn_mfma_f32_16x16x32_bf16(af, bf, acc[t], 0, 0, 0);
        }
    }

    // bias + bf16 store via per-wave LDS transpose (C/D: row=q*4+reg, col=16t+c)
    #pragma unroll
    for (int t = 0; t < 4; ++t) {
        const float bv = bias[t * 16 + c];
        #pragma unroll
        for (int r = 0; r < 4; ++r)
            ctile[w][q * 4 + r][t * 16 + c] = f2bf(acc[t][r] + bv);
    }
    const int row = lane >> 2, eo = (lane & 3) * 16;
    const uint4 v0 = *(const uint4*)(&ctile[w][row][eo]);
    const uint4 v1 = *(const uint4*)(&ctile[w][row][eo + 8]);
    *(uint4*)(C + (size_t)(rw0 + row) * 64 + eo)     = v0;
    *(uint4*)(C + (size_t)(rw0 + row) * 64 + eo + 8) = v1;
}

// ---------------- layer GEMM: C = A[M x 64] @ w, + attn dots ------------------
// A bf16 row-major, WT bf16 [n][k]. Emits C bf16 and hs/hd fp32 (pre-bias).
__global__ __launch_bounds__(256) void gemm_layer(
    const ushort* __restrict__ A, const ushort* __restrict__ WT,
    const float* __restrict__ a_s, const float* __restrict__ a_d,
    ushort* __restrict__ C, float* __restrict__ hs, float* __restrict__ hd, int M)
{
    __shared__ __align__(16) ushort ctile[4][16][64];
    const int tid = threadIdx.x;
    const int w = tid >> 6, lane = tid & 63;
    const int rw0 = (blockIdx.x * 4 + w) * 16;
    if (rw0 >= M) return;
    const int c = lane & 15, q = lane >> 4;

    const ushort* ap = A + (size_t)(rw0 + c) * 64 + q * 8;
    const bf16x8 a0 = *(const bf16x8*)(ap);
    const bf16x8 a1 = *(const bf16x8*)(ap + 32);

    f32x4 acc[4];
    #pragma unroll
    for (int t = 0; t < 4; ++t) {
        const ushort* bp = WT + (size_t)(t * 16 + c) * 64 + q * 8;
        const bf16x8 b0 = *(const bf16x8*)(bp);
        const bf16x8 b1 = *(const bf16x8*)(bp + 32);
        f32x4 a = (f32x4){0.f, 0.f, 0.f, 0.f};
        a = __builtin_amdgcn_mfma_f32_16x16x32_bf16(a0, b0, a, 0, 0, 0);
        a = __builtin_amdgcn_mfma_f32_16x16x32_bf16(a1, b1, a, 0, 0, 0);
        acc[t] = a;
    }

    // attn dots: hs[r] = sum_n C[r][n]*a_s[n]; lane holds cols {16t+c}
    float ps[4] = {0.f, 0.f, 0.f, 0.f}, pd[4] = {0.f, 0.f, 0.f, 0.f};
    #pragma unroll
    for (int t = 0; t < 4; ++t) {
        const float as = a_s[t * 16 + c], ad = a_d[t * 16 + c];
        #pragma unroll
        for (int r = 0; r < 4; ++r) {
            ps[r] = fmaf(acc[t][r], as, ps[r]);
            pd[r] = fmaf(acc[t][r], ad, pd[r]);
        }
    }
    #pragma unroll
    for (int r = 0; r < 4; ++r) {
        #pragma unroll
        for (int off = 1; off < 16; off <<= 1) {
            ps[r] += __shfl_xor(ps[r], off);
            pd[r] += __shfl_xor(pd[r], off);
        }
    }
    if (c == 0) {
        #pragma unroll
        for (int r = 0; r < 4; ++r) {
            hs[rw0 + q * 4 + r] = ps[r];
            hd[rw0 + q * 4 + r] = pd[r];
        }
    }

    // bf16 store via per-wave LDS transpose
    #pragma unroll
    for (int t = 0; t < 4; ++t)
        #pragma unroll
        for (int r = 0; r < 4; ++r)
            ctile[w][q * 4 + r][t * 16 + c] = f2bf(acc[t][r]);
    const int row = lane >> 2, eo = (lane & 3) * 16;
    const uint4 v0 = *(const uint4*)(&ctile[w][row][eo]);
    const uint4 v1 = *(const uint4*)(&ctile[w][row][eo + 8]);
    *(uint4*)(C + (size_t)(rw0 + row) * 64 + eo)     = v0;
    *(uint4*)(C + (size_t)(rw0 + row) * 64 + eo + 8) = v1;
}

// ---------------- CSR build --------------------------------------------------
__global__ __launch_bounds__(256) void edge_hist(
    const int* __restrict__ dst, int* __restrict__ cnt, int e)
{
    const int i = blockIdx.x * blockDim.x + threadIdx.x;
    if (i < e) atomicAdd(&cnt[dst[i]], 1);
}

__global__ __launch_bounds__(256) void scan1(
    const int* __restrict__ cnt, int* __restrict__ out,
    int* __restrict__ bsum, int n)
{
    __shared__ int wsum[4];
    const int tid  = threadIdx.x;
    const int lane = tid & 63;
    const int w    = tid >> 6;
    const int base = blockIdx.x * 1024;
    int vals[4];
    int tsum = 0;
    #pragma unroll
    for (int i = 0; i < 4; ++i) {
        const int idx = base + tid * 4 + i;
        vals[i] = (idx < n) ? cnt[idx] : 0;
        tsum += vals[i];
    }
    int x = tsum;
    #pragma unroll
    for (int off = 1; off < 64; off <<= 1) {
        const int y = __shfl_up(x, off);
        if (lane >= off) x += y;
    }
    if (lane == 63) wsum[w] = x;
    __syncthreads();
    int wofs = 0;
    for (int k = 0; k < w; ++k) wofs += wsum[k];
    int excl = wofs + x - tsum;
    #pragma unroll
    for (int i = 0; i < 4; ++i) {
        const int idx = base + tid * 4 + i;
        if (idx < n) out[idx] = excl;
        excl += vals[i];
    }
    if (tid == 255) bsum[blockIdx.x] = wofs + x;
}

__global__ __launch_bounds__(128) void scan2(int* __restrict__ b, int nb)
{
    __shared__ int wtot[2];
    const int tid = threadIdx.x;
    const int lane = tid & 63;
    const int w = tid >> 6;
    const int v = (tid < nb) ? b[tid] : 0;
    int x = v;
    #pragma unroll
    for (int off = 1; off < 64; off <<= 1) {
        const int y = __shfl_up(x, off);
        if (lane >= off) x += y;
    }
    if (lane == 63) wtot[w] = x;
    __syncthreads();
    const int add = (w == 1) ? wtot[0] : 0;
    if (tid < nb) b[tid] = add + x - v;
}

__global__ __launch_bounds__(256) void scan3(
    int* __restrict__ out, const int* __restrict__ bsum, int n, int total)
{
    const int idx = blockIdx.x * blockDim.x + threadIdx.x;
    if (idx < n) out[idx] += bsum[idx >> 10];
    if (idx == 0) out[n] = total;
}

__global__ __launch_bounds__(256) void cursor_init(
    const int* __restrict__ offs, int* __restrict__ gcur, int n, int nb)
{
    const int b = threadIdx.x;
    if (b < nb) gcur[b] = offs[min(b << BKT_SHIFT, n)];
}

// Phase 1: bucket edges by dst>>9 into CSR-aligned regions, coalesced runs.
// 2-pass over the global chunk (2nd read is L2-hot) — no scratch spill.
__global__ __launch_bounds__(256) void edge_partition(
    const int* __restrict__ src, const int* __restrict__ dst,
    int* __restrict__ gcursor, int2* __restrict__ pairs, int e, int nb)
{
    __shared__ int2 stage[PCHUNK];
    __shared__ int lcnt[256];
    __shared__ int lstart[256];
    __shared__ int lfill[256];
    __shared__ int gbase[256];
    __shared__ int wsum[4];

    const int tid  = threadIdx.x;
    const int lane = tid & 63;
    const int w    = tid >> 6;
    const int base = blockIdx.x * PCHUNK;
    const int cnt_here = min(PCHUNK, e - base);

    lcnt[tid] = 0; lfill[tid] = 0;
    __syncthreads();

    // pass 1: bucket histogram
    for (int i = tid; i < cnt_here; i += 256)
        atomicAdd(&lcnt[dst[base + i] >> BKT_SHIFT], 1);
    __syncthreads();

    // exclusive scan of lcnt[256] -> lstart; reserve global runs
    const int v = lcnt[tid];
    int x = v;
    #pragma unroll
    for (int off = 1; off < 64; off <<= 1) {
        const int y = __shfl_up(x, off);
        if (lane >= off) x += y;
    }
    if (lane == 63) wsum[w] = x;
    __syncthreads();
    int carry = 0;
    for (int k = 0; k < w; ++k) carry += wsum[k];
    lstart[tid] = carry + x - v;
    if (tid < nb && v > 0) gbase[tid] = atomicAdd(&gcursor[tid], v);
    __syncthreads();

    // pass 2: re-read (L2-hot) and stage bucket-major in LDS
    for (int i = tid; i < cnt_here; i += 256) {
        int2 it; it.x = src[base + i]; it.y = dst[base + i];
        const int b = it.y >> BKT_SHIFT;
        const int p = lstart[b] + atomicAdd(&lfill[b], 1);
        stage[p] = it;
    }
    __syncthreads();

    // contiguous write-out per bucket run
    for (int s = tid; s < cnt_here; s += 256) {
        const int2 it = stage[s];
        const int b = it.y >> BKT_SHIFT;
        pairs[gbase[b] + (s - lstart[b])] = it;
    }
}

// Phase 2: one block per bucket; per-node cursors in LDS; writes confined
// to this block's contiguous ssrc region (single-XCD line merging).
__global__ __launch_bounds__(256) void bucket_scatter(
    const int2* __restrict__ pairs, const int* __restrict__ offs,
    int* __restrict__ ssrc, int n)
{
    __shared__ int pos[BKT_N];
    const int node0 = blockIdx.x << BKT_SHIFT;
    const int node1 = min(n, node0 + BKT_N);
    const int tid = threadIdx.x;
    for (int i = tid; i < node1 - node0; i += 256) pos[i] = offs[node0 + i];
    __syncthreads();
    const int e0 = offs[node0];
    const int e1 = offs[node1];
    for (int j = e0 + tid; j < e1; j += 256) {
        const int2 it = pairs[j];
        const int p = atomicAdd(&pos[it.y - node0], 1);
        ssrc[p] = it.x;
    }
}

// ---------------- gather aggregation (bf16 rows) -----------------------------
// One wave per node; 8 edge slots x 8 lanes (16 B = 8 bf16 per lane).
// MODE 0: +bias, ReLU -> bf16 out.  MODE 1: +bias, L2 normalize -> fp32 out.
template <int MODE>
__global__ __launch_bounds__(256) void gat_agg(
    const ushort* __restrict__ hp, const float* __restrict__ hs,
    const float* __restrict__ hd, const int* __restrict__ offs,
    const int* __restrict__ ssrc, const float* __restrict__ bias,
    void* __restrict__ outv, int n)
{
    const int wid  = (blockIdx.x * blockDim.x + threadIdx.x) >> 6;
    const int lane = threadIdx.x & 63;
    if (wid >= n) return;
    const int sub = lane >> 3;          // edge slot 0..7
    const int f0  = (lane & 7) * 8;     // feature offset (8 bf16)

    const float hdi = hd[wid];
    float den = 0.f;
    float acc[8] = {};

    if (sub == 0) {   // self-loop
        float e = hs[wid] + hdi;
        e = (e > 0.f) ? e : NEG_SLOPE * e;
        const float ex = __expf(e);
        const uint4 t = *(const uint4*)(hp + (size_t)wid * 64 + f0);
        float f[8];
        bf2f(t.x, f[0], f[1]); bf2f(t.y, f[2], f[3]);
        bf2f(t.z, f[4], f[5]); bf2f(t.w, f[6], f[7]);
        den = ex;
        #pragma unroll
        for (int i = 0; i < 8; ++i) acc[i] = ex * f[i];
    }

    const int start = offs[wid];
    const int end   = offs[wid + 1];
    #pragma unroll 2
    for (int j = start + sub; j < end; j += 8) {
        const int s = ssrc[j];
        float e2 = hs[s] + hdi;
        e2 = (e2 > 0.f) ? e2 : NEG_SLOPE * e2;
        const float ex2 = __expf(e2);
        const uint4 t = *(const uint4*)(hp + (size_t)s * 64 + f0);
        float f[8];
        bf2f(t.x, f[0], f[1]); bf2f(t.y, f[2], f[3]);
        bf2f(t.z, f[4], f[5]); bf2f(t.w, f[6], f[7]);
        den += ex2;
        #pragma unroll
        for (int i = 0; i < 8; ++i) acc[i] = fmaf(ex2, f[i], acc[i]);
    }

    // reduce the 8 edge slots (lanes with same f0)
    #pragma unroll
    for (int off = 8; off < 64; off <<= 1) {
        den += __shfl_xor(den, off);
        #pragma unroll
        for (int i = 0; i < 8; ++i) acc[i] += __shfl_xor(acc[i], off);
    }

    const float4 bv0 = *(const float4*)(bias + f0);
    const float4 bv1 = *(const float4*)(bias + f0 + 4);
    const float bb[8] = {bv0.x, bv0.y, bv0.z, bv0.w, bv1.x, bv1.y, bv1.z, bv1.w};
    const float inv = 1.f / (den + 1e-16f);
    float v[8];
    #pragma unroll
    for (int i = 0; i < 8; ++i) v[i] = acc[i] * inv + bb[i];

    if (MODE == 0) {
        #pragma unroll
        for (int i = 0; i < 8; ++i) v[i] = fmaxf(v[i], 0.f);
        if (sub == 0) {
            uint4 o;
            o.x = pk(v[0], v[1]); o.y = pk(v[2], v[3]);
            o.z = pk(v[4], v[5]); o.w = pk(v[6], v[7]);
            *(uint4*)((ushort*)outv + (size_t)wid * 64 + f0) = o;
        }
    } else {
        float sq = 0.f;
        #pragma unroll
        for (int i = 0; i < 8; ++i) sq += v[i] * v[i];
        #pragma unroll
        for (int off = 1; off < 8; off <<= 1) sq += __shfl_xor(sq, off);
        const float s = 1.f / fmaxf(sqrtf(sq), 1e-12f);
        if (sub == 0) {
            float* op = (float*)outv + (size_t)wid * 64 + f0;
            float4 o0, o1;
            o0.x = v[0] * s; o0.y = v[1] * s; o0.z = v[2] * s; o0.w = v[3] * s;
            o1.x = v[4] * s; o1.y = v[5] * s; o1.z = v[6] * s; o1.w = v[7] * s;
            *(float4*)(op)     = o0;
            *(float4*)(op + 4) = o1;
        }
    }
}

// ---------------- launch -----------------------------------------------------
extern "C" void kernel_launch(void* const* d_in, const int* in_sizes, int n_in,
                              void* d_out, int out_size, void* d_ws, size_t ws_size,
                              hipStream_t stream)
{
    const float* x     = (const float*)d_in[0];
    const int*   src   = (const int*)d_in[1];
    const int*   dst   = (const int*)d_in[2];
    const float* lin_w = (const float*)d_in[3];
    const float* lin_b = (const float*)d_in[4];
    const float* w1  = (const float*)d_in[5];
    const float* a1s = (const float*)d_in[6];
    const float* a1d = (const float*)d_in[7];
    const float* b1  = (const float*)d_in[8];
    const float* w2  = (const float*)d_in[9];
    const float* a2s = (const float*)d_in[10];
    const float* a2d = (const float*)d_in[11];
    const float* b2  = (const float*)d_in[12];
    const float* w3  = (const float*)d_in[13];
    const float* a3s = (const float*)d_in[14];
    const float* a3d = (const float*)d_in[15];
    const float* b3  = (const float*)d_in[16];

    const int n = in_sizes[0] / 256;   // 100000 nodes
    const int E = in_sizes[1];         // 1280000 edges
    const int nb = (n + BKT_N - 1) >> BKT_SHIFT;

    char* wsp = (char*)d_ws;
    auto alloc = [&](size_t bytes) -> void* {
        void* p = (void*)wsp;
        wsp += (bytes + 255) & ~(size_t)255;
        return p;
    };
    ushort* bufA = (ushort*)alloc((size_t)n * 64 * sizeof(ushort));   // bf16 h
    ushort* bufB = (ushort*)alloc((size_t)n * 64 * sizeof(ushort));   // bf16 h'
    float*  hs   = (float*)alloc((size_t)n * sizeof(float));
    float*  hd   = (float*)alloc((size_t)n * sizeof(float));
    int*    offs = (int*)alloc((size_t)(n + 1) * sizeof(int));
    int*    cnt  = (int*)alloc((size_t)n * sizeof(int));
    int*    bsum = (int*)alloc(1024 * sizeof(int));
    int*    gcur = (int*)alloc(256 * sizeof(int));
    int*    ssrc = (int*)alloc((size_t)E * sizeof(int));
    int2*   pairs = (int2*)alloc((size_t)E * sizeof(int2));
    ushort* lwT = (ushort*)alloc(64 * 256 * sizeof(ushort));
    ushort* w1T = (ushort*)alloc(64 * 64 * sizeof(ushort));
    ushort* w2T = (ushort*)alloc(64 * 64 * sizeof(ushort));
    ushort* w3T = (ushort*)alloc(64 * 64 * sizeof(ushort));

    const int edgeBlocks = (E + 255) / 256;
    const int nodeWaveBlocks = (n + 3) / 4;
    const int gemmBlocks = (n + 63) / 64;
    const int nScanBlocks = (n + 1023) / 1024;
    const int partBlocks = (E + PCHUNK - 1) / PCHUNK;

    // ---- weight prep + CSR build ----
    prep_w<<<(64 * 256 + 4096 + 255) / 256, 256, 0, stream>>>(
        lin_w, w1, w2, w3, lwT, w1T, w2T, w3T);
    hipMemsetAsync(cnt, 0, (size_t)n * sizeof(int), stream);
    edge_hist<<<edgeBlocks, 256, 0, stream>>>(dst, cnt, E);
    scan1<<<nScanBlocks, 256, 0, stream>>>(cnt, offs, bsum, n);
    scan2<<<1, 128, 0, stream>>>(bsum, nScanBlocks);
    scan3<<<(n + 255) / 256, 256, 0, stream>>>(offs, bsum, n, E);
    cursor_init<<<1, 256, 0, stream>>>(offs, gcur, n, nb);
    edge_partition<<<partBlocks, 256, 0, stream>>>(src, dst, gcur, pairs, E, nb);
    bucket_scatter<<<nb, 256, 0, stream>>>(pairs, offs, ssrc, n);

    // ---- h0 = bf16(x @ lin_w + lin_b) ----
    gemm_pre<<<gemmBlocks, 256, 0, stream>>>(x, lwT, lin_b, bufA, n);

    // ---- layer 1 ----
    gemm_layer<<<gemmBlocks, 256, 0, stream>>>(bufA, w1T, a1s, a1d, bufB, hs, hd, n);
    gat_agg<0><<<nodeWaveBlocks, 256, 0, stream>>>(bufB, hs, hd, offs, ssrc, b1, bufA, n);

    // ---- layer 2 ----
    gemm_layer<<<gemmBlocks, 256, 0, stream>>>(bufA, w2T, a2s, a2d, bufB, hs, hd, n);
    gat_agg<0><<<nodeWaveBlocks, 256, 0, stream>>>(bufB, hs, hd, offs, ssrc, b2, bufA, n);

    // ---- layer 3 + normalize -> d_out ----
    gemm_layer<<<gemmBlocks, 256, 0, stream>>>(bufA, w3T, a3s, a3d, bufB, hs, hd, n);
    gat_agg<1><<<nodeWaveBlocks, 256, 0, stream>>>(bufB, hs, hd, offs, ssrc, b3,
                                                   d_out, n);
}